// Round 20
// baseline (511.533 us; speedup 1.0000x reference)
//
#include <hip/hip_runtime.h>
#include <hip/hip_bf16.h>

#define N_TOK   2048
#define DIM     1024
#define HEADS   16
#define DH      64
#define WBLK    32
#define NSEL    8
#define CD      4096

typedef __hip_bfloat16 bf16;
typedef __attribute__((ext_vector_type(8))) short short8;
typedef __attribute__((ext_vector_type(4))) float f32x4;

// ================= async global->LDS (16B per lane) =================
__device__ __forceinline__ void gll16(const void* g, void* l) {
    __builtin_amdgcn_global_load_lds((const __attribute__((address_space(1))) void*)g,
                                     (__attribute__((address_space(3))) void*)l, 16, 0, 0);
}

// ================= MFMA GEMM: C = act(A@B + bias) =================
// BM=64, BN=64, BK=32; 4 waves 2x2, wave tile 32x32. 3-buffer counted-vmcnt pipeline.
// A: bf16 splits [M][K]; B: TRANSPOSED bf16 splits [N][K].
// PAIRS: 1 ; 3 = split2 3-term ; 4 = exact split2^2 ; 6 = split3.
// OUT: 0 = f32 C ; 2 = split2 bf16 C0,C1 ; 3 = f32 C + split2 C0,C1 ;
//      5 = f32 C + permuted cmat split2 (pe added) ; 6 = f32 C + permuted cmat single.
template<int PAIRS, int OUT>
__global__ __launch_bounds__(256, 2) void gemm_mfma(
    const bf16* __restrict__ a0, const bf16* __restrict__ a1, const bf16* __restrict__ a2,
    const bf16* __restrict__ b0, const bf16* __restrict__ b1, const bf16* __restrict__ b2,
    const float* __restrict__ bias, float* __restrict__ C,
    bf16* __restrict__ C0, bf16* __restrict__ C1,
    int M, int N, int K, int act, const float* __restrict__ pe)
{
    constexpr int NS = (PAIRS == 6) ? 3 : ((PAIRS >= 3) ? 2 : 1);
    __shared__ __align__(16) bf16 As[3][NS][64][32];
    __shared__ __align__(16) bf16 Bs[3][NS][64][32];

    const int tid = threadIdx.x, lane = tid & 63, wid = tid >> 6;
    const int wr = wid >> 1, wc = wid & 1;
    const int row0 = blockIdx.y * 64, col0 = blockIdx.x * 64;

    const bf16* ap[3] = {a0, a1, a2};
    const bf16* bp[3] = {b0, b1, b2};

    f32x4 acc[2][2];
    #pragma unroll
    for (int mi = 0; mi < 2; ++mi)
        #pragma unroll
        for (int ni = 0; ni < 2; ++ni) acc[mi][ni] = (f32x4){0.f, 0.f, 0.f, 0.f};

    const int lr = lane >> 2;
    const int lc = (((lane & 3) ^ ((lane >> 3) & 3))) * 8;
    const int fo = (((lane >> 4) ^ ((lane >> 1) & 3))) * 8;

    constexpr int pa[6] = {0, 0, 1, 1, 0, 2};
    constexpr int pb[6] = {0, 1, 0, 1, 2, 0};

    auto stage = [&](int buf, int t) {
        const int k0 = t << 5;
        #pragma unroll
        for (int s = 0; s < NS; ++s) {
            gll16(ap[s] + (size_t)(row0 + wid * 16 + lr) * K + k0 + lc, &As[buf][s][wid * 16][0]);
            gll16(bp[s] + (size_t)(col0 + wid * 16 + lr) * K + k0 + lc, &Bs[buf][s][wid * 16][0]);
        }
    };

    const int nt = K >> 5;
    stage(0, 0);
    if (nt > 1) {
        stage(1, 1);
        asm volatile("s_waitcnt vmcnt(%0)" :: "n"(2 * NS) : "memory");
    } else {
        asm volatile("s_waitcnt vmcnt(0)" ::: "memory");
    }
    __builtin_amdgcn_s_barrier();

    for (int t = 0; t < nt; ++t) {
        const int cur = t % 3;

        short8 af[2][NS], bfr[2][NS];
        #pragma unroll
        for (int mi = 0; mi < 2; ++mi)
            #pragma unroll
            for (int s = 0; s < NS; ++s)
                af[mi][s] = *(const short8*)&As[cur][s][wr * 32 + mi * 16 + (lane & 15)][fo];
        #pragma unroll
        for (int ni = 0; ni < 2; ++ni)
            #pragma unroll
            for (int s = 0; s < NS; ++s)
                bfr[ni][s] = *(const short8*)&Bs[cur][s][wc * 32 + ni * 16 + (lane & 15)][fo];

        if (t + 2 < nt) stage((t + 2) % 3, t + 2);

        #pragma unroll
        for (int mi = 0; mi < 2; ++mi)
            #pragma unroll
            for (int ni = 0; ni < 2; ++ni) {
                f32x4 c = acc[mi][ni];
                #pragma unroll
                for (int p = 0; p < PAIRS; ++p)
                    c = __builtin_amdgcn_mfma_f32_16x16x32_bf16(af[mi][pa[p]], bfr[ni][pb[p]], c, 0, 0, 0);
                acc[mi][ni] = c;
            }

        if (t + 1 < nt) {
            if (t + 2 < nt) asm volatile("s_waitcnt vmcnt(%0)" :: "n"(2 * NS) : "memory");
            else            asm volatile("s_waitcnt vmcnt(0)" ::: "memory");
            __builtin_amdgcn_s_barrier();
        }
    }

    #pragma unroll
    for (int mi = 0; mi < 2; ++mi)
        #pragma unroll
        for (int ni = 0; ni < 2; ++ni)
            #pragma unroll
            for (int r = 0; r < 4; ++r) {
                int row = row0 + wr * 32 + mi * 16 + (lane >> 4) * 4 + r;
                int col = col0 + wc * 32 + ni * 16 + (lane & 15);
                float v = acc[mi][ni][r];
                if (bias) v += bias[col];
                if (act == 1) v = fmaxf(v, 0.f);
                if (OUT == 0 || OUT == 3 || OUT == 5 || OUT == 6) C[(size_t)row * N + col] = v;
                if (OUT == 2 || OUT == 3) {
                    bf16 hh = __float2bfloat16(v);
                    C0[(size_t)row * N + col] = hh;
                    C1[(size_t)row * N + col] = __float2bfloat16(v - __bfloat162float(hh));
                }
                if (OUT == 5 || OUT == 6) {
                    int w_ = row >> 6, pos = row & 63, hh_ = col >> 6, d_ = col & 63;
                    float xx = v + pe[(size_t)((pos << 4) + hh_) * 64 + d_];
                    size_t ci = ((size_t)((w_ << 4) + hh_) << 12) + (pos << 6) + d_;
                    bf16 bb = __float2bfloat16(xx);
                    C0[ci] = bb;
                    if (OUT == 5) C1[ci] = __float2bfloat16(xx - __bfloat162float(bb));
                }
            }
}

// ================= big-tile split-K GEMM for compress L1 =================
// BM=128, BN=128, BK=32; 4 waves 2x2, wave tile 64x64 (acc 4x4); KC=4 via blockIdx.z.
// 2-buffer drain schedule (R17 config, best measured). Split-K accumulation via
// f32 atomicAdd into an 8.4MB L2-resident accumulator (pre-filled with bias) --
// removes the 33.5MB partial write + 33.5MB read HBM round-trip.
template<int PAIRS>
__global__ __launch_bounds__(256, 2) void gemm_bigk(
    const bf16* __restrict__ a0, const bf16* __restrict__ a1,
    const bf16* __restrict__ b0, const bf16* __restrict__ b1,
    float* __restrict__ hacc, int M, int N, int K)
{
    constexpr int NS = (PAIRS >= 3) ? 2 : 1;
    __shared__ __align__(16) bf16 As[2][NS][128][32];
    __shared__ __align__(16) bf16 Bs[2][NS][128][32];

    const int tid = threadIdx.x, lane = tid & 63, wid = tid >> 6;
    const int wr = wid >> 1, wc = wid & 1;
    const int row0 = blockIdx.y * 128, col0 = blockIdx.x * 128;
    const int kchunk = K >> 2;
    const int kbase = blockIdx.z * kchunk;

    const bf16* ap[2] = {a0, a1};
    const bf16* bp[2] = {b0, b1};

    f32x4 acc[4][4];
    #pragma unroll
    for (int mi = 0; mi < 4; ++mi)
        #pragma unroll
        for (int ni = 0; ni < 4; ++ni) acc[mi][ni] = (f32x4){0.f, 0.f, 0.f, 0.f};

    const int lr = lane >> 2;
    const int lc = (((lane & 3) ^ ((lane >> 3) & 3))) * 8;
    const int fo = (((lane >> 4) ^ ((lane >> 1) & 3))) * 8;

    constexpr int pa[3] = {0, 0, 1};
    constexpr int pb[3] = {0, 1, 0};

    auto stage = [&](int buf, int t) {
        const int k0 = kbase + (t << 5);
        #pragma unroll
        for (int s = 0; s < NS; ++s) {
            gll16(ap[s] + (size_t)(row0 + wid * 32 + lr) * K + k0 + lc,      &As[buf][s][wid * 32][0]);
            gll16(ap[s] + (size_t)(row0 + wid * 32 + 16 + lr) * K + k0 + lc, &As[buf][s][wid * 32 + 16][0]);
            gll16(bp[s] + (size_t)(col0 + wid * 32 + lr) * K + k0 + lc,      &Bs[buf][s][wid * 32][0]);
            gll16(bp[s] + (size_t)(col0 + wid * 32 + 16 + lr) * K + k0 + lc, &Bs[buf][s][wid * 32 + 16][0]);
        }
    };

    const int nt = kchunk >> 5;
    stage(0, 0);
    __syncthreads();

    for (int t = 0; t < nt; ++t) {
        const int cur = t & 1;
        if (t + 1 < nt) stage(cur ^ 1, t + 1);

        short8 af[4][NS], bfr[4][NS];
        #pragma unroll
        for (int mi = 0; mi < 4; ++mi)
            #pragma unroll
            for (int s = 0; s < NS; ++s)
                af[mi][s] = *(const short8*)&As[cur][s][wr * 64 + mi * 16 + (lane & 15)][fo];
        #pragma unroll
        for (int ni = 0; ni < 4; ++ni)
            #pragma unroll
            for (int s = 0; s < NS; ++s)
                bfr[ni][s] = *(const short8*)&Bs[cur][s][wc * 64 + ni * 16 + (lane & 15)][fo];

        #pragma unroll
        for (int mi = 0; mi < 4; ++mi)
            #pragma unroll
            for (int ni = 0; ni < 4; ++ni) {
                f32x4 c = acc[mi][ni];
                #pragma unroll
                for (int p = 0; p < PAIRS; ++p)
                    c = __builtin_amdgcn_mfma_f32_16x16x32_bf16(af[mi][pa[p]], bfr[ni][pb[p]], c, 0, 0, 0);
                acc[mi][ni] = c;
            }
        __syncthreads();
    }

    #pragma unroll
    for (int mi = 0; mi < 4; ++mi)
        #pragma unroll
        for (int ni = 0; ni < 4; ++ni)
            #pragma unroll
            for (int r = 0; r < 4; ++r) {
                int row = row0 + wr * 64 + mi * 16 + (lane >> 4) * 4 + r;
                int col = col0 + wc * 64 + ni * 16 + (lane & 15);
                atomicAdd(&hacc[(size_t)row * N + col], acc[mi][ni][r]);
            }
}

// hinit: pre-fill split-K accumulator with bias
__global__ void hinit(float* __restrict__ hacc, const float* __restrict__ bias) {
    int i = blockIdx.x * 256 + threadIdx.x;
    hacc[i] = bias[i & (CD - 1)];
}

// kredh: relu + split2 of the atomically-accumulated h
__global__ void kredh(const float* __restrict__ hacc,
                      bf16* __restrict__ h0, bf16* __restrict__ h1) {
    int i = blockIdx.x * 256 + threadIdx.x;
    float s = fmaxf(hacc[i], 0.f);
    bf16 hh = __float2bfloat16(s);
    h0[i] = hh;
    h1[i] = __float2bfloat16(s - __bfloat162float(hh));
}

// ================= split-K skinny MFMA GEMM (3-buffer pipeline) =================
template<int KC>
__global__ __launch_bounds__(256, 2) void sk_gemm(
    const bf16* __restrict__ a0, const bf16* __restrict__ a1,
    const bf16* __restrict__ b0, const bf16* __restrict__ b1,
    float* __restrict__ part, int M, int K)
{
    __shared__ __align__(16) bf16 As[3][2][64][32];
    __shared__ __align__(16) bf16 Bs[3][2][64][32];
    const int tid = threadIdx.x, lane = tid & 63, wid = tid >> 6;
    const int wr = wid >> 1, wc = wid & 1;
    const int row0 = blockIdx.x * 64;
    const int kchunk = K / KC;
    const int kbase = blockIdx.y * kchunk;
    const bf16* ap[2] = {a0, a1};
    const bf16* bp[2] = {b0, b1};
    const int lr = lane >> 2;
    const int lc = (((lane & 3) ^ ((lane >> 3) & 3))) * 8;
    const int fo = (((lane >> 4) ^ ((lane >> 1) & 3))) * 8;

    f32x4 acc[2][2];
    #pragma unroll
    for (int mi = 0; mi < 2; ++mi)
        #pragma unroll
        for (int ni = 0; ni < 2; ++ni) acc[mi][ni] = (f32x4){0.f, 0.f, 0.f, 0.f};

    auto stage = [&](int buf, int t) {
        const int k0 = kbase + (t << 5);
        #pragma unroll
        for (int s = 0; s < 2; ++s) {
            gll16(ap[s] + (size_t)(row0 + wid * 16 + lr) * K + k0 + lc, &As[buf][s][wid * 16][0]);
            gll16(bp[s] + (size_t)(wid * 16 + lr) * K + k0 + lc,        &Bs[buf][s][wid * 16][0]);
        }
    };

    const int nt = kchunk >> 5;
    stage(0, 0);
    if (nt > 1) {
        stage(1, 1);
        asm volatile("s_waitcnt vmcnt(4)" ::: "memory");
    } else {
        asm volatile("s_waitcnt vmcnt(0)" ::: "memory");
    }
    __builtin_amdgcn_s_barrier();

    for (int t = 0; t < nt; ++t) {
        const int cur = t % 3;
        short8 af[2][2], bfr[2][2];
        #pragma unroll
        for (int mi = 0; mi < 2; ++mi)
            #pragma unroll
            for (int s = 0; s < 2; ++s)
                af[mi][s] = *(const short8*)&As[cur][s][wr * 32 + mi * 16 + (lane & 15)][fo];
        #pragma unroll
        for (int ni = 0; ni < 2; ++ni)
            #pragma unroll
            for (int s = 0; s < 2; ++s)
                bfr[ni][s] = *(const short8*)&Bs[cur][s][wc * 32 + ni * 16 + (lane & 15)][fo];

        if (t + 2 < nt) stage((t + 2) % 3, t + 2);

        #pragma unroll
        for (int mi = 0; mi < 2; ++mi)
            #pragma unroll
            for (int ni = 0; ni < 2; ++ni) {
                f32x4 c = acc[mi][ni];
                c = __builtin_amdgcn_mfma_f32_16x16x32_bf16(af[mi][0], bfr[ni][0], c, 0, 0, 0);
                c = __builtin_amdgcn_mfma_f32_16x16x32_bf16(af[mi][0], bfr[ni][1], c, 0, 0, 0);
                c = __builtin_amdgcn_mfma_f32_16x16x32_bf16(af[mi][1], bfr[ni][0], c, 0, 0, 0);
                acc[mi][ni] = c;
            }

        if (t + 1 < nt) {
            if (t + 2 < nt) asm volatile("s_waitcnt vmcnt(4)" ::: "memory");
            else            asm volatile("s_waitcnt vmcnt(0)" ::: "memory");
            __builtin_amdgcn_s_barrier();
        }
    }

    #pragma unroll
    for (int mi = 0; mi < 2; ++mi)
        #pragma unroll
        for (int ni = 0; ni < 2; ++ni)
            #pragma unroll
            for (int r = 0; r < 4; ++r) {
                int row = row0 + wr * 32 + mi * 16 + (lane >> 4) * 4 + r;
                int col = wc * 32 + ni * 16 + (lane & 15);
                part[((size_t)blockIdx.y * M + row) * 64 + col] = acc[mi][ni][r];
            }
}

// skred: reduce split-K partials; optionally emit split2 bf16 of the result
__global__ void skred(const float* __restrict__ part, const float* __restrict__ bias,
                      float* __restrict__ C, bf16* __restrict__ C0, bf16* __restrict__ C1,
                      int M, int KC) {
    int i = blockIdx.x * 256 + threadIdx.x;
    if (i >= M * 64) return;
    float s = bias ? bias[i & 63] : 0.f;
    for (int kc = 0; kc < KC; ++kc) s += part[(size_t)kc * M * 64 + i];
    C[i] = s;
    if (C0) {
        bf16 hh = __float2bfloat16(s);
        C0[i] = hh;
        C1[i] = __float2bfloat16(s - __bfloat162float(hh));
    }
}

// ================= cscore GEMM via MFMA (also zeroes counts) =================
__global__ __launch_bounds__(256) void cscore_gemm(const bf16* __restrict__ qs0,
                                                   const bf16* __restrict__ qs1,
                                                   const bf16* __restrict__ ck0,
                                                   const bf16* __restrict__ ck1,
                                                   float* __restrict__ Sc,
                                                   int* __restrict__ counts) {
    if (blockIdx.x == 0 && blockIdx.y == 0) {
        counts[threadIdx.x] = 0;
        counts[threadIdx.x + 256] = 0;
    }
    int h = blockIdx.y;
    int wid = threadIdx.x >> 6, lane = threadIdx.x & 63;
    int q0 = blockIdx.x * 128 + wid * 32;
    const int lr = lane & 15, hc = lane >> 4;

    f32x4 acc[2][2];
    #pragma unroll
    for (int a = 0; a < 2; ++a)
        #pragma unroll
        for (int b = 0; b < 2; ++b) acc[a][b] = (f32x4){0.f, 0.f, 0.f, 0.f};

    short8 av[2][2][2], bv[2][2][2];
    #pragma unroll
    for (int qs_ = 0; qs_ < 2; ++qs_)
        #pragma unroll
        for (int ks = 0; ks < 2; ++ks) {
            size_t off = ((size_t)(q0 + qs_ * 16 + lr) << 10) + (h << 6) + ks * 32 + hc * 8;
            av[qs_][ks][0] = *(const short8*)(qs0 + off);
            av[qs_][ks][1] = *(const short8*)(qs1 + off);
        }
    #pragma unroll
    for (int ws = 0; ws < 2; ++ws)
        #pragma unroll
        for (int ks = 0; ks < 2; ++ks) {
            size_t off = ((size_t)(((ws * 16 + lr) << 4) + h)) * 64 + ks * 32 + hc * 8;
            bv[ws][ks][0] = *(const short8*)(ck0 + off);
            bv[ws][ks][1] = *(const short8*)(ck1 + off);
        }
    #pragma unroll
    for (int qs_ = 0; qs_ < 2; ++qs_)
        #pragma unroll
        for (int ws = 0; ws < 2; ++ws) {
            f32x4 c = acc[qs_][ws];
            #pragma unroll
            for (int ks = 0; ks < 2; ++ks) {
                c = __builtin_amdgcn_mfma_f32_16x16x32_bf16(av[qs_][ks][0], bv[ws][ks][0], c, 0, 0, 0);
                c = __builtin_amdgcn_mfma_f32_16x16x32_bf16(av[qs_][ks][0], bv[ws][ks][1], c, 0, 0, 0);
                c = __builtin_amdgcn_mfma_f32_16x16x32_bf16(av[qs_][ks][1], bv[ws][ks][0], c, 0, 0, 0);
            }
            acc[qs_][ws] = c;
        }
    #pragma unroll
    for (int qs_ = 0; qs_ < 2; ++qs_)
        #pragma unroll
        for (int ws = 0; ws < 2; ++ws)
            #pragma unroll
            for (int r = 0; r < 4; ++r) {
                int q = q0 + qs_ * 16 + hc * 4 + r;
                int w = ws * 16 + lr;
                Sc[((size_t)(h << 11) + q) * 32 + w] = acc[qs_][ws][r] * 0.125f;
            }
}

// ================= softmax + rank-based top-8 + compressed PV =================
__global__ __launch_bounds__(256) void ctopk_pv(const float* __restrict__ Sc,
                                                const float* __restrict__ cv,
                                                float* __restrict__ comp,
                                                int* __restrict__ idxb) {
    int item = blockIdx.x * 4 + (threadIdx.x >> 6);
    int lane = threadIdx.x & 63;
    int h = item >> 11, qpos = item & 2047;
    float logit = (lane < 32) ? Sc[(size_t)item * 32 + lane] : -1e30f;
    float m = logit;
    #pragma unroll
    for (int o = 32; o; o >>= 1) m = fmaxf(m, __shfl_xor(m, o));
    float e = (lane < 32) ? expf(logit - m) : 0.f;
    float s = e;
    #pragma unroll
    for (int o = 32; o; o >>= 1) s += __shfl_xor(s, o);
    float inv = 1.f / s;
    float acc = 0.f;
    #pragma unroll 8
    for (int w = 0; w < WBLK; ++w) {
        float pw = __shfl(e, w) * inv;
        acc += pw * cv[(size_t)((w << 4) + h) * 64 + lane];
    }
    comp[(size_t)(qpos << 10) + (h << 6) + lane] = acc;
    int rank = 0;
    #pragma unroll 8
    for (int j = 0; j < WBLK; ++j) {
        float lj = __shfl(logit, j);
        rank += (lj > logit || (lj == logit && j < lane)) ? 1 : 0;
    }
    if (lane < 32 && rank < NSEL) idxb[item * NSEL + rank] = lane;
}

// ================= gate: sigmoid(x @ Wc + bc) =================
__global__ __launch_bounds__(256) void gate_gemm(const float* __restrict__ x,
                                                 const float* __restrict__ Wc,
                                                 const float* __restrict__ bc,
                                                 float* __restrict__ gate) {
    __shared__ float xr[1024];
    __shared__ float part[8][32];
    int row = blockIdx.x;
    #pragma unroll
    for (int i = 0; i < 4; ++i)
        xr[threadIdx.x + i * 256] = x[(size_t)row * 1024 + threadIdx.x + i * 256];
    __syncthreads();
    int c = threadIdx.x & 31, sl = threadIdx.x >> 5;
    float acc = 0.f;
    for (int k = sl; k < 1024; k += 8) acc += xr[k] * Wc[k * 32 + c];
    part[sl][c] = acc;
    __syncthreads();
    if (sl == 0) {
        float v = bc[c];
        #pragma unroll
        for (int j = 0; j < 8; ++j) v += part[j][c];
        gate[(size_t)row * 32 + c] = 1.f / (1.f + expf(-v));
    }
}

// ================= transpose + split =================
template<int NS>
__global__ __launch_bounds__(256) void tsplit(const float* __restrict__ B,
                                              bf16* __restrict__ t0, bf16* __restrict__ t1,
                                              bf16* __restrict__ t2, int K, int N) {
    __shared__ float tile[32][33];
    int tx = threadIdx.x & 31, ty = threadIdx.x >> 5;
    int bx = blockIdx.x, by = blockIdx.y;
    #pragma unroll
    for (int i = 0; i < 4; ++i)
        tile[ty + i * 8][tx] = B[(size_t)(by * 32 + ty + i * 8) * N + bx * 32 + tx];
    __syncthreads();
    #pragma unroll
    for (int i = 0; i < 4; ++i) {
        int nn = bx * 32 + ty + i * 8;
        int kk = by * 32 + tx;
        float x = tile[tx][ty + i * 8];
        bf16 h = __float2bfloat16(x);
        t0[(size_t)nn * K + kk] = h;
        if (NS >= 2) {
            float r1 = x - __bfloat162float(h);
            bf16 m = __float2bfloat16(r1);
            t1[(size_t)nn * K + kk] = m;
            if (NS == 3) t2[(size_t)nn * K + kk] = __float2bfloat16(r1 - __bfloat162float(m));
        }
    }
}

// ================= elementwise split =================
__global__ void split2_k(const float* __restrict__ s, bf16* __restrict__ d0,
                         bf16* __restrict__ d1, int n) {
    int i = blockIdx.x * 256 + threadIdx.x;
    if (i >= n) return;
    float x = s[i];
    bf16 h = __float2bfloat16(x); d0[i] = h;
    d1[i] = __float2bfloat16(x - __bfloat162float(h));
}

// ================= fallback helpers =================
__global__ void build_cmat(const float* __restrict__ kv, const float* __restrict__ pe,
                           float* __restrict__ cmat) {
    int i = blockIdx.x * 256 + threadIdx.x;
    int r = i >> 12, c = i & 4095;
    int w = r >> 4, h = r & 15;
    int pos = c >> 6, d = c & 63;
    cmat[i] = kv[(size_t)((w * 64 + pos) << 10) + (h << 6) + d] +
              pe[(size_t)((pos << 4) + h) * 64 + d];
}

__global__ __launch_bounds__(256) void gemm_skinny64(const float* __restrict__ A,
                                                     const float* __restrict__ B,
                                                     const float* __restrict__ bias,
                                                     float* __restrict__ C, int K) {
    __shared__ float Arow[4096];
    __shared__ float part[4][64];
    int row = blockIdx.x;
    for (int i = threadIdx.x; i < K; i += 256) Arow[i] = A[(size_t)row * K + i];
    __syncthreads();
    int c = threadIdx.x & 63, sl = threadIdx.x >> 6;
    float acc = 0.f;
    for (int k = sl; k < K; k += 4) acc += Arow[k] * B[(size_t)k * 64 + c];
    part[sl][c] = acc;
    __syncthreads();
    if (sl == 0) {
        float v = part[0][c] + part[1][c] + part[2][c] + part[3][c];
        if (bias) v += bias[c];
        C[(size_t)row * 64 + c] = v;
    }
}

__global__ __launch_bounds__(256) void gemm_f32(const float* __restrict__ A,
                                                const float* __restrict__ B,
                                                const float* __restrict__ bias,
                                                float* __restrict__ C,
                                                int M, int N, int K, int act) {
    __shared__ float As[16][65];
    __shared__ float Bs[16][65];
    const int tid  = threadIdx.x;
    const int row0 = blockIdx.y * 64;
    const int col0 = blockIdx.x * 64;
    const int tm = tid >> 4;
    const int tn = tid & 15;

    float acc[4][4];
    #pragma unroll
    for (int i = 0; i < 4; ++i)
        #pragma unroll
        for (int j = 0; j < 4; ++j) acc[i][j] = 0.f;

    const int ar  = tid >> 2;
    const int akq = (tid & 3) << 2;

    for (int k0 = 0; k0 < K; k0 += 16) {
        float4 a4 = make_float4(0.f, 0.f, 0.f, 0.f);
        if (row0 + ar < M)
            a4 = *reinterpret_cast<const float4*>(&A[(size_t)(row0 + ar) * K + k0 + akq]);
        As[akq + 0][ar] = a4.x; As[akq + 1][ar] = a4.y;
        As[akq + 2][ar] = a4.z; As[akq + 3][ar] = a4.w;
        #pragma unroll
        for (int it = 0; it < 4; ++it) {
            int idx = tid + it * 256;
            int kr = idx >> 6, c = idx & 63;
            float bv = 0.f;
            if (col0 + c < N) bv = B[(size_t)(k0 + kr) * N + col0 + c];
            Bs[kr][c] = bv;
        }
        __syncthreads();
        #pragma unroll
        for (int kk = 0; kk < 16; ++kk) {
            float a0 = As[kk][tm * 4 + 0], a1 = As[kk][tm * 4 + 1];
            float a2 = As[kk][tm * 4 + 2], a3 = As[kk][tm * 4 + 3];
            float b0v = Bs[kk][tn * 4 + 0], b1v = Bs[kk][tn * 4 + 1];
            float b2v = Bs[kk][tn * 4 + 2], b3v = Bs[kk][tn * 4 + 3];
            acc[0][0] += a0 * b0v; acc[0][1] += a0 * b1v; acc[0][2] += a0 * b2v; acc[0][3] += a0 * b3v;
            acc[1][0] += a1 * b0v; acc[1][1] += a1 * b1v; acc[1][2] += a1 * b2v; acc[1][3] += a1 * b3v;
            acc[2][0] += a2 * b0v; acc[2][1] += a2 * b1v; acc[2][2] += a2 * b2v; acc[2][3] += a2 * b3v;
            acc[3][0] += a3 * b0v; acc[3][1] += a3 * b1v; acc[3][2] += a3 * b2v; acc[3][3] += a3 * b3v;
        }
        __syncthreads();
    }

    #pragma unroll
    for (int i = 0; i < 4; ++i) {
        int r = row0 + tm * 4 + i;
        if (r >= M) continue;
        #pragma unroll
        for (int j = 0; j < 4; ++j) {
            int cc = col0 + tn * 4 + j;
            if (cc >= N) continue;
            float vv = acc[i][j];
            if (bias) vv += bias[cc];
            if (act == 1) vv = fmaxf(vv, 0.f);
            else if (act == 2) vv = 1.f / (1.f + expf(-vv));
            C[(size_t)r * N + cc] = vv;
        }
    }
}

__global__ __launch_bounds__(256) void cscore_topk(const float* __restrict__ q,
                                                   const float* __restrict__ ck,
                                                   float* __restrict__ cprob,
                                                   int* __restrict__ idxb) {
    int item = blockIdx.x * 4 + (threadIdx.x >> 6);
    int lane = threadIdx.x & 63;
    int h = item >> 11;
    int qpos = item & 2047;
    float qv = q[(size_t)(qpos << 10) + (h << 6) + lane];
    float logit = -1e30f;
    const float scale = 0.125f;
    for (int w = 0; w < WBLK; ++w) {
        float p = qv * ck[(size_t)((w << 4) + h) * 64 + lane];
        #pragma unroll
        for (int o = 32; o; o >>= 1) p += __shfl_xor(p, o);
        if (lane == w) logit = p * scale;
    }
    float m = logit;
    #pragma unroll
    for (int o = 32; o; o >>= 1) m = fmaxf(m, __shfl_xor(m, o));
    float e = (lane < 32) ? expf(logit - m) : 0.f;
    float s = e;
    #pragma unroll
    for (int o = 32; o; o >>= 1) s += __shfl_xor(s, o);
    if (lane < 32) cprob[(size_t)item * WBLK + lane] = e / s;
    float vcur = logit;
    for (int t = 0; t < NSEL; ++t) {
        float bm = vcur; int bi = lane;
        #pragma unroll
        for (int o = 32; o; o >>= 1) {
            float om = __shfl_xor(bm, o); int oi = __shfl_xor(bi, o);
            if (om > bm || (om == bm && oi < bi)) { bm = om; bi = oi; }
        }
        if (lane == 0) idxb[item * NSEL + t] = bi;
        if (lane == bi) vcur = -1e30f;
    }
}
__global__ void compressed_pv(const float* __restrict__ cprob, const float* __restrict__ cv,
                              float* __restrict__ comp) {
    int i = blockIdx.x * 256 + threadIdx.x;
    int qpos = i >> 10; int hd = i & 1023; int h = hd >> 6; int d = hd & 63;
    const float* pr = &cprob[(size_t)(h * N_TOK + qpos) * WBLK];
    float acc = 0.f;
    #pragma unroll
    for (int w = 0; w < WBLK; ++w) acc += pr[w] * cv[(size_t)((w << 4) + h) * 64 + d];
    comp[i] = acc;
}

__global__ void rope_ip(float* __restrict__ q, float* __restrict__ k,
                        const float* __restrict__ fc) {
    int i = blockIdx.x * 256 + threadIdx.x;
    int n = i >> 9; int hp = i & 511; int h = hp >> 5; int p = hp & 31;
    float c = fc[(size_t)(n * 32 + p) * 2];
    float s = fc[(size_t)(n * 32 + p) * 2 + 1];
    size_t base = (size_t)(n << 10) + (h << 6) + (p << 1);
    float qr = q[base], qi = q[base + 1];
    q[base] = qr * c - qi * s; q[base + 1] = qr * s + qi * c;
    float kr = k[base], ki = k[base + 1];
    k[base] = kr * c - ki * s; k[base + 1] = kr * s + ki * c;
}

// ================= fused RoPE + bf16 convert for q,k =================
__global__ void rope_convert_qk(const float* __restrict__ q, const float* __restrict__ k,
                                const float* __restrict__ fc,
                                bf16* __restrict__ qb, bf16* __restrict__ kb) {
    int i = blockIdx.x * 256 + threadIdx.x;
    int n = i >> 9; int hp = i & 511; int h = hp >> 5; int p = hp & 31;
    float c = fc[(size_t)(n * 32 + p) * 2];
    float s = fc[(size_t)(n * 32 + p) * 2 + 1];
    size_t base = (size_t)(n << 10) + (h << 6) + (p << 1);
    float qr = q[base], qi = q[base + 1];
    qb[base]     = __float2bfloat16(0.125f * (qr * c - qi * s));
    qb[base + 1] = __float2bfloat16(0.125f * (qr * s + qi * c));
    float kr = k[base], ki = k[base + 1];
    kb[base]     = __float2bfloat16(kr * c - ki * s);
    kb[base + 1] = __float2bfloat16(kr * s + ki * c);
}

// ================= coalesced V transpose =================
__global__ __launch_bounds__(256) void convert_vT(const float* __restrict__ v,
                                                  bf16* __restrict__ vbT) {
    __shared__ float tile[64][65];
    int h = blockIdx.x;
    int n0 = blockIdx.y * 64;
    int tx = threadIdx.x & 63, ty = threadIdx.x >> 6;
    #pragma unroll
    for (int i = 0; i < 16; ++i)
        tile[ty + 4 * i][tx] = v[(size_t)(n0 + ty + 4 * i) * 1024 + (h << 6) + tx];
    __syncthreads();
    #pragma unroll
    for (int i = 0; i < 16; ++i) {
        int d = ty + 4 * i;
        vbT[((size_t)(h << 6) + d) * 2048 + n0 + tx] = __float2bfloat16(tile[tx][d]);
    }
}

// ================= hierarchical build_lists =================
__global__ __launch_bounds__(256) void build_lists(const int* __restrict__ idxb,
                                                   int* __restrict__ counts,
                                                   int* __restrict__ lists) {
    __shared__ int lcnt[32];
    __shared__ int gbase[32];
    int h = blockIdx.x >> 3;
    int q = ((blockIdx.x & 7) << 8) + threadIdx.x;
    if (threadIdx.x < 32) lcnt[threadIdx.x] = 0;
    __syncthreads();
    int item = (h << 11) + q;
    int wv[NSEL], lo[NSEL];
    #pragma unroll
    for (int t = 0; t < NSEL; ++t) {
        wv[t] = idxb[item * NSEL + t];
        lo[t] = atomicAdd(&lcnt[wv[t]], 1);
    }
    __syncthreads();
    if (threadIdx.x < 32)
        gbase[threadIdx.x] = atomicAdd(&counts[(h << 5) + threadIdx.x], lcnt[threadIdx.x]);
    __syncthreads();
    #pragma unroll
    for (int t = 0; t < NSEL; ++t) {
        int g = (h << 5) + wv[t];
        lists[g * 2048 + gbase[wv[t]] + lo[t]] = (q << 3) | t;
    }
}

__global__ void convert_qkv(const float* __restrict__ q, const float* __restrict__ k,
                            const float* __restrict__ v, bf16* __restrict__ qb,
                            bf16* __restrict__ kb, bf16* __restrict__ vbT) {
    int i = blockIdx.x * 256 + threadIdx.x;
    qb[i] = __float2bfloat16(0.125f * q[i]);
    kb[i] = __float2bfloat16(k[i]);
    int h = i >> 17, d = (i >> 11) & 63, n = i & 2047;
    vbT[i] = __float2bfloat16(v[(size_t)(n << 10) + (h << 6) + d]);
}

__global__ __launch_bounds__(64) void sel_scores(const bf16* __restrict__ qb,
                                                 const bf16* __restrict__ kb,
                                                 const int* __restrict__ counts,
                                                 const int* __restrict__ lists,
                                                 float* __restrict__ S) {
    int g = blockIdx.x;
    int cnt = counts[g];
    int tile = blockIdx.y;
    if (tile * 32 >= cnt) return;
    int h = g >> 5, w = g & 31;
    int lane = threadIdx.x;
    __shared__ int qt[32];
    __shared__ float st[32][66];
    int nrow = cnt - tile * 32; if (nrow > 32) nrow = 32;
    if (lane < 32) qt[lane] = lists[g * 2048 + tile * 32 + (lane < nrow ? lane : nrow - 1)];
    __syncthreads();
    int lr = lane & 15, hc = lane >> 4;

    f32x4 acc[2][4];
    #pragma unroll
    for (int m = 0; m < 2; ++m)
        #pragma unroll
        for (int gk = 0; gk < 4; ++gk) acc[m][gk] = (f32x4){0.f, 0.f, 0.f, 0.f};

    short8 a[2][2], b[4][2];
    #pragma unroll
    for (int m = 0; m < 2; ++m) {
        int qq = qt[m * 16 + lr] >> 3;
        const bf16* ar = qb + ((size_t)qq << 10) + (h << 6) + hc * 8;
        a[m][0] = *(const short8*)ar;
        a[m][1] = *(const short8*)(ar + 32);
    }
    #pragma unroll
    for (int gk = 0; gk < 4; ++gk) {
        const bf16* kr = kb + ((size_t)((w << 6) + gk * 16 + lr) << 10) + (h << 6) + hc * 8;
        b[gk][0] = *(const short8*)kr;
        b[gk][1] = *(const short8*)(kr + 32);
    }
    #pragma unroll
    for (int m = 0; m < 2; ++m)
        #pragma unroll
        for (int gk = 0; gk < 4; ++gk) {
            acc[m][gk] = __builtin_amdgcn_mfma_f32_16x16x32_bf16(a[m][0], b[gk][0], acc[m][gk], 0, 0, 0);
            acc[m][gk] = __builtin_amdgcn_mfma_f32_16x16x32_bf16(a[m][1], b[gk][1], acc[m][gk], 0, 0, 0);
        }
    #pragma unroll
    for (int m = 0; m < 2; ++m)
        #pragma unroll
        for (int gk = 0; gk < 4; ++gk)
            #pragma unroll
            for (int r = 0; r < 4; ++r)
                st[m * 16 + hc * 4 + r][gk * 16 + lr] = acc[m][gk][r];
    __syncthreads();
    for (int rr = 0; rr < nrow; ++rr) {
        int e = qt[rr]; int qq = e >> 3, t = e & 7;
        S[((size_t)((h << 11) + qq) << 9) + (t << 6) + lane] = st[rr][lane];
    }
}

__global__ __launch_bounds__(256) void sel_softmax(const float* __restrict__ S,
                                                   bf16* __restrict__ P) {
    int item = blockIdx.x * 4 + (threadIdx.x >> 6);
    int lane = threadIdx.x & 63;
    const float* row = S + ((size_t)item << 9);
    float v[8]; float m = -1e30f;
    #pragma unroll
    for (int j = 0; j < 8; ++j) { v[j] = row[(j << 6) + lane]; m = fmaxf(m, v[j]); }
    #pragma unroll
    for (int o = 32; o; o >>= 1) m = fmaxf(m, __shfl_xor(m, o));
    float s = 0.f;
    #pragma unroll
    for (int j = 0; j < 8; ++j) { v[j] = expf(v[j] - m); s += v[j]; }
    #pragma unroll
    for (int o = 32; o; o >>= 1) s += __shfl_xor(s, o);
    float inv = 1.f / s;
    #pragma unroll
    for (int j = 0; j < 8; ++j)
        P[((size_t)item << 9) + (j << 6) + lane] = __float2bfloat16(v[j] * inv);
}

// Phase D: gathered PV GEMM -> Opart[item][t][64] in bf16
__global__ __launch_bounds__(64) void sel_pv(const bf16* __restrict__ P,
                                             const bf16* __restrict__ vbT,
                                             const int* __restrict__ counts,
                                             const int* __restrict__ lists,
                                             bf16* __restrict__ Opart) {
    int g = blockIdx.x;
    int cnt = counts[g];
    int tile = blockIdx.y;
    if (tile * 32 >= cnt) return;
    int h = g >> 5, w = g & 31;
    int lane = threadIdx.x;
    __shared__ int qt[32];
    __shared__ float st[32][66];
    int nrow = cnt - tile * 32; if (nrow > 32) nrow = 32;
    if (lane < 32) qt[lane] = lists[g * 2048 + tile * 32 + (lane < nrow ? lane : nrow - 1)];
    __syncthreads();
    int lr = lane & 15, hc = lane >> 4;

    f32x4 acc[2][4];
    #pragma unroll
    for (int m = 0; m < 2; ++m)
        #pragma unroll
        for (int dg = 0; dg < 4; ++dg) acc[m][dg] = (f32x4){0.f, 0.f, 0.f, 0.f};

    short8 a[2][2], b[4][2];
    #pragma unroll
    for (int m = 0; m < 2; ++m) {
        int e = qt[m * 16 + lr]; int qq = e >> 3, t = e & 7;
        const bf16* pr = P + ((size_t)((h << 11) + qq) << 9) + (t << 6) + hc * 8;
        a[m][0] = *(const short8*)pr;
        a[m][1] = *(const short8*)(pr + 32);
    }
    #pragma unroll
    for (int dg = 0; dg < 4; ++dg) {
        const bf16* vr = vbT + ((size_t)((h << 6) + dg * 16 + lr) << 11) + (w << 6) + hc * 8;
        b[dg][0] = *(const short8*)vr;
        b[dg][1] = *(const short8*)(vr + 32);
    }
    #pragma unroll
    for (int m = 0; m < 2; ++m)
        #pragma unroll
        for (int dg = 0; dg < 4; ++dg) {
            acc[m][dg] = __builtin_amdgcn_mfma_f32_16x16x32_bf16(a[m][0], b[dg][0], acc[m][dg], 0, 0, 0);
            acc[m][dg] = __builtin_amdgcn_mfma_f32_16x16x32_bf16(a[m][1], b[dg][1], acc[m][dg], 0, 0, 0);
        }
    #pragma unroll
    for (int m = 0; m < 2; ++m)
        #pragma unroll
        for (int dg = 0; dg < 4; ++dg)
            #pragma unroll
            for (int r = 0; r < 4; ++r)
                st[m * 16 + hc * 4 + r][dg * 16 + lr] = acc[m][dg][r];
    __syncthreads();
    for (int rr = 0; rr < nrow; ++rr) {
        int e = qt[rr]; int qq = e >> 3, t = e & 7;
        Opart[((size_t)((h << 11) + qq) << 9) + (t << 6) + lane] = __float2bfloat16(st[rr][lane]);
    }
}

// Phase E: y = g0*comp + g1*sum_t Opart, emitted directly as split2 bf16
__global__ void sel_combine(const bf16* __restrict__ Opart, const float* __restrict__ comp,
                            const float* __restrict__ gate,
                            bf16* __restrict__ y0, bf16* __restrict__ y1) {
    int i = blockIdx.x * 256 + threadIdx.x;
    int qpos = i >> 10, hd = i & 1023, h = hd >> 6, d = hd & 63;
    size_t base = ((size_t)((h << 11) + qpos) << 9) + d;
    float s = 0.f;
    #pragma unroll
    for (int t = 0; t < 8; ++t) s += __bfloat162float(Opart[base + (t << 6)]);
    float g0 = gate[(size_t)qpos * 32 + h];
    float g1 = gate[(size_t)qpos * 32 + 16 + h];
    float val = g0 * comp[i] + g1 * s;
    bf16 b0 = __float2bfloat16(val);
    y0[i] = b0;
    y1[i] = __float2bfloat16(val - __bfloat162float(b0));
}

// ================= fallback fused selected attention =================
__global__ __launch_bounds__(64) void selected_attn(const float* __restrict__ sq,
                                                    const float* __restrict__ sk,
                                                    const float* __restrict__ v,
                                                    const int* __restrict__ idxb,
                                                    const float* __restrict__ comp,
                                                    const float* __restrict__ gate,
                                                    float* __restrict__ y) {
    __shared__ float tile[64][65];
    __shared__ float sqs[64];
    __shared__ float pls[64];
    int item = blockIdx.x;
    int h = item >> 11, qpos = item & 2047;
    int lane = threadIdx.x;
    sqs[lane] = sq[(size_t)(qpos << 10) + (h << 6) + lane];
    int idx[NSEL];
    #pragma unroll
    for (int t = 0; t < NSEL; ++t) idx[t] = idxb[item * NSEL + t];

    const float scale = 0.125f;
    float sc[NSEL];
    float m = -1e30f;
    for (int t = 0; t < NSEL; ++t) {
        int w = idx[t];
        __syncthreads();
        for (int r = 0; r < 64; ++r)
            tile[r][lane] = sk[(size_t)((w << 6) + r) * 1024 + (h << 6) + lane];
        __syncthreads();
        float acc = 0.f;
        #pragma unroll
        for (int d = 0; d < 64; ++d) acc += sqs[d] * tile[lane][d];
        sc[t] = acc * scale;
        m = fmaxf(m, sc[t]);
    }
    #pragma unroll
    for (int o = 32; o; o >>= 1) m = fmaxf(m, __shfl_xor(m, o));
    float p[NSEL];
    float denom = 0.f;
    #pragma unroll
    for (int t = 0; t < NSEL; ++t) { p[t] = expf(sc[t] - m); denom += p[t]; }
    #pragma unroll
    for (int o = 32; o; o >>= 1) denom += __shfl_xor(denom, o);
    float inv = 1.f / denom;

    float acc = 0.f;
    for (int t = 0; t < NSEL; ++t) {
        int w = idx[t];
        __syncthreads();
        for (int r = 0; r < 64; ++r)
            tile[r][lane] = v[(size_t)((w << 6) + r) * 1024 + (h << 6) + lane];
        pls[lane] = p[t];
        __syncthreads();
        #pragma unroll
        for (int j = 0; j < 64; ++j) acc += pls[j] * tile[j][lane];
    }
    acc *= inv;

    float g0 = gate[(size_t)qpos * 32 + h];
    float g1 = gate[(size_t)qpos * 32 + 16 + h];
    size_t o = (size_t)(qpos << 10) + (h << 6) + lane;
    y[o] = g0 * comp[o] + g1 * acc;
}

extern "C" void kernel_launch(void* const* d_in, const int* in_sizes, int n_in,
                              void* d_out, int out_size, void* d_ws, size_t ws_size,
                              hipStream_t stream) {
    const float* x   = (const float*)d_in[0];
    const float* fc  = (const float*)d_in[1];
    const float* Wq  = (const float*)d_in[2];
    const float* Wk  = (const float*)d_in[3];
    const float* Wv  = (const float*)d_in[4];
    const float* Wo  = (const float*)d_in[5];
    const float* pe  = (const float*)d_in[6];
    const float* kW1 = (const float*)d_in[7];
    const float* kb1 = (const float*)d_in[8];
    const float* kW2 = (const float*)d_in[9];
    const float* kb2 = (const float*)d_in[10];
    const float* vW1 = (const float*)d_in[11];
    const float* vb1 = (const float*)d_in[12];
    const float* vW2 = (const float*)d_in[13];
    const float* vb2 = (const float*)d_in[14];
    const float* Wc  = (const float*)d_in[15];
    const float* bc  = (const float*)d_in[16];
    float* out = (float*)d_out;

    char* base = (char*)d_ws;
    size_t off = 0;
    auto alloc = [&](size_t bytes) -> void* {
        void* r = base + off;
        off += (bytes + 255) & ~(size_t)255;
        return r;
    };
    const size_t E2M = 2097152;   // 2048*1024
    float* q     = (float*)alloc(E2M * 4);
    float* k     = (float*)alloc(E2M * 4);
    float* v     = (float*)alloc(E2M * 4);
    float* gate  = (float*)alloc(N_TOK * 32 * 4);
    float* comp  = (float*)alloc(E2M * 4);
    float* hreg  = (float*)alloc(E2M * 4);     // hosts h0,h1 bf16 splits
    float* y     = (float*)alloc(E2M * 4);     // hosts sk_gemm partials + Sc
    float* ck    = (float*)alloc(512 * 64 * 4);
    float* cv    = (float*)alloc(512 * 64 * 4);
    float* cprob = (float*)alloc((size_t)HEADS * N_TOK * WBLK * 4);
    int*   idxb  = (int*)alloc((size_t)HEADS * N_TOK * NSEL * 4);
    bf16* xs0 = (bf16*)alloc(E2M * 2);
    bf16* xs1 = (bf16*)alloc(E2M * 2);
    bf16* WqT0 = (bf16*)alloc((size_t)DIM * DIM * 2);
    bf16* WqT1 = (bf16*)alloc((size_t)DIM * DIM * 2);
    bf16* WkT0 = (bf16*)alloc((size_t)DIM * DIM * 2);
    bf16* WkT1 = (bf16*)alloc((size_t)DIM * DIM * 2);
    bf16* WvT  = (bf16*)alloc((size_t)DIM * DIM * 2);
    bf16* WoT0 = (bf16*)alloc((size_t)DIM * DIM * 2);
    bf16* WoT1 = (bf16*)alloc((size_t)DIM * DIM * 2);
    bf16* kW1T0 = (bf16*)alloc((size_t)CD * CD * 2);   // later aliased by S/Opart
    bf16* kW1T1 = (bf16*)alloc((size_t)CD * CD * 2);
    bf16* vW1T  = (bf16*)alloc((size_t)CD * CD * 2);
    bf16* kW2T0 = (bf16*)alloc((size_t)64 * CD * 2);
    bf16* kW2T1 = (bf16*)alloc((size_t)64 * CD * 2);
    bf16* vW2T0 = (bf16*)alloc((size_t)64 * CD * 2);
    bf16* vW2T1 = (bf16*)alloc((size_t)64 * CD * 2);
    bf16* cm0 = (bf16*)alloc(E2M * 2);
    bf16* cm1 = (bf16*)alloc(E2M * 2);
    bf16* cmv0 = (bf16*)alloc(E2M * 2);
    bf16* y0  = (bf16*)alloc(E2M * 2);
    bf16* y1  = (bf16*)alloc(E2M * 2);
    int*  counts = (int*)alloc(512 * 4);
    int*  lists  = (int*)alloc((size_t)512 * 2048 * 4);
    bf16* qb     = (bf16*)alloc(E2M * 2);
    bf16* kb     = (bf16*)alloc(E2M * 2);
    bf16* vbT    = (bf16*)alloc(E2M * 2);
    bf16* ck0    = (bf16*)alloc(512 * 64 * 2);
    bf16* ck1    = (bf16*)alloc(512 * 64 * 2);
    bf16* Pbuf   = (bf16*)alloc((size_t)HEADS * N_TOK * 512 * 2);   // 33.6 MB
    // aliases
    bf16*  h0     = (bf16*)hreg;                   // 4 MB
    bf16*  h1     = h0 + (size_t)512 * CD;         // 4 MB
    float* part   = y;                             // sk_gemm partials (8 MB)
    float* Sc     = y;                             // cscore logits
    bf16*  qs0    = y0;                            // q split2 (y0/y1 free until Wo stage)
    bf16*  qs1    = y1;
    float* hacc   = (float*)Pbuf;                  // 8.4MB f32 split-K accumulator (L2-resident)
    float* S      = (float*)kW1T0;                 // sel scores (67 MB over dead weight splits)
    bf16*  P      = Pbuf;
    bf16*  Opart  = kW1T0;                         // bf16 partials (33.5 MB, S dead after softmax)

    dim3 blk(256);
    if (off <= ws_size) {
        // ---------- fast path ----------
        split2_k<<<8192, 256, 0, stream>>>(x, xs0, xs1, (int)E2M);
        tsplit<2><<<dim3(32, 32), blk, 0, stream>>>(Wq, WqT0, WqT1, nullptr, DIM, DIM);
        tsplit<2><<<dim3(32, 32), blk, 0, stream>>>(Wk, WkT0, WkT1, nullptr, DIM, DIM);
        tsplit<1><<<dim3(32, 32), blk, 0, stream>>>(Wv, WvT, nullptr, nullptr, DIM, DIM);
        tsplit<2><<<dim3(32, 32), blk, 0, stream>>>(Wo, WoT0, WoT1, nullptr, DIM, DIM);
        tsplit<2><<<dim3(128, 128), blk, 0, stream>>>(kW1, kW1T0, kW1T1, nullptr, CD, CD);
        tsplit<1><<<dim3(128, 128), blk, 0, stream>>>(vW1, vW1T, nullptr, nullptr, CD, CD);
        tsplit<2><<<dim3(2, 128), blk, 0, stream>>>(kW2, kW2T0, kW2T1, nullptr, CD, 64);
        tsplit<2><<<dim3(2, 128), blk, 0, stream>>>(vW2, vW2T0, vW2T1, nullptr, CD, 64);

        // projections (R14 BM=64 config); Wk/Wv epilogues emit cmat
        gemm_mfma<4, 3><<<dim3(16, 32), blk, 0, stream>>>(xs0, xs1, nullptr, WqT0, WqT1, nullptr,
                                                          nullptr, q, qs0, qs1, N_TOK, DIM, DIM, 0, nullptr);
        gemm_mfma<4, 5><<<dim3(16, 32), blk, 0, stream>>>(xs0, xs1, nullptr, WkT0, WkT1, nullptr,
                                                          nullptr, k, cm0, cm1, N_TOK, DIM, DIM, 0, pe);
        gemm_mfma<1, 6><<<dim3(16, 32), blk, 0, stream>>>(xs0, nullptr, nullptr, WvT, nullptr, nullptr,
                                                          nullptr, v, cmv0, nullptr, N_TOK, DIM, DIM, 0, pe);
        gate_gemm<<<2048, blk, 0, stream>>>(x, Wc, bc, gate);

        // k-compress: 128x128-tile split-K(4) with atomic accumulation into L2-resident hacc
        hinit<<<8192, 256, 0, stream>>>(hacc, kb1);
        gemm_bigk<3><<<dim3(32, 4, 4), blk, 0, stream>>>(cm0, cm1, kW1T0, kW1T1, hacc, 512, CD, CD);
        kredh<<<8192, 256, 0, stream>>>(hacc, h0, h1);
        sk_gemm<64><<<dim3(8, 64), blk, 0, stream>>>(h0, h1, kW2T0, kW2T1, part, 512, CD);
        skred<<<128, 256, 0, stream>>>(part, kb2, ck, ck0, ck1, 512, 64);

        // v-compress
        hinit<<<8192, 256, 0, stream>>>(hacc, vb1);
        gemm_bigk<1><<<dim3(32, 4, 4), blk, 0, stream>>>(cmv0, nullptr, vW1T, nullptr, hacc, 512, CD, CD);
        kredh<<<8192, 256, 0, stream>>>(hacc, h0, h1);
        sk_gemm<64><<<dim3(8, 64), blk, 0, stream>>>(h0, h1, vW2T0, vW2T1, part, 512, CD);
        skred<<<128, 256, 0, stream>>>(part, vb2, cv, nullptr, nullptr, 512, 64);

        // cscore via MFMA (also zeroes counts), then softmax + rank-top8 + PV
        cscore_gemm<<<dim3(16, 16), blk, 0, stream>>>(qs0, qs1, ck0, ck1, Sc, counts);
        ctopk_pv<<<8192, 256, 0, stream>>>(Sc, cv, comp, idxb);

        // RoPE fused into bf16 conversion; coalesced V transpose
        rope_convert_qk<<<4096, 256, 0, stream>>>(q, k, fc, qb, kb);
        convert_vT<<<dim3(16, 32), blk, 0, stream>>>(v, vbT);

        build_lists<<<128, 256, 0, stream>>>(idxb, counts, lists);
        sel_scores<<<dim3(512, 64), 64, 0, stream>>>(qb, kb, counts, lists, S);
        sel_softmax<<<8192, 256, 0, stream>>>(S, P);
        sel_pv<<<dim3(512, 64), 64, 0, stream>>>(P, vbT, counts, lists, Opart);
        sel_combine<<<8192, 256, 0, stream>>>(Opart, comp, gate, y0, y1);

        gemm_mfma<3, 0><<<dim3(16, 32), blk, 0, stream>>>(y0, y1, nullptr, WoT0, WoT1, nullptr,
                                                          nullptr, out, nullptr, nullptr, N_TOK, DIM, DIM, 0, nullptr);
    } else {
        // ---------- fallback: f32 path ----------
        char* p = (char*)d_ws;
        float* fq    = (float*)p;               p += E2M * 4;
        float* fk    = (float*)p;               p += E2M * 4;
        float* fv    = (float*)p;               p += E2M * 4;
        float* fgate = (float*)p;               p += N_TOK * 32 * 4;
        float* cmat  = (float*)p;               p += E2M * 4;
        float* hbuf  = (float*)p;               p += E2M * 4;
        float* fck   = (float*)p;               p += 512 * 64 * 4;
        float* fcv   = (float*)p;               p += 512 * 64 * 4;
        float* fcpr  = (float*)p;               p += (size_t)HEADS * N_TOK * WBLK * 4;
        int*   fidx  = (int*)p;
        float* fcomp = cmat;
        float* fy    = hbuf;

        gemm_f32<<<dim3(16, 32), blk, 0, stream>>>(x, Wq, nullptr, fq, N_TOK, DIM, DIM, 0);
        gemm_f32<<<dim3(16, 32), blk, 0, stream>>>(x, Wk, nullptr, fk, N_TOK, DIM, DIM, 0);
        gemm_f32<<<dim3(16, 32), blk, 0, stream>>>(x, Wv, nullptr, fv, N_TOK, DIM, DIM, 0);
        gemm_f32<<<dim3(1, 32),  blk, 0, stream>>>(x, Wc, bc, fgate, N_TOK, 2 * HEADS, DIM, 2);
        build_cmat<<<8192, 256, 0, stream>>>(fk, pe, cmat);
        gemm_f32<<<dim3(64, 8), blk, 0, stream>>>(cmat, kW1, kb1, hbuf, 512, CD, CD, 1);
        gemm_skinny64<<<512, blk, 0, stream>>>(hbuf, kW2, kb2, fck, CD);
        build_cmat<<<8192, 256, 0, stream>>>(fv, pe, cmat);
        gemm_f32<<<dim3(64, 8), blk, 0, stream>>>(cmat, vW1, vb1, hbuf, 512, CD, CD, 1);
        gemm_skinny64<<<512, blk, 0, stream>>>(hbuf, vW2, vb2, fcv, CD);
        cscore_topk<<<8192, 256, 0, stream>>>(fq, fck, fcpr, fidx);
        compressed_pv<<<8192, 256, 0, stream>>>(fcpr, fcv, fcomp);
        rope_ip<<<4096, 256, 0, stream>>>(fq, fk, fc);
        selected_attn<<<32768, 64, 0, stream>>>(fq, fk, fv, fidx, fcomp, fgate, fy);
        gemm_f32<<<dim3(16, 32), blk, 0, stream>>>(fy, Wo, nullptr, out, N_TOK, DIM, DIM, 0);
    }
}

// Round 21
// 473.867 us; speedup vs baseline: 1.0795x; 1.0795x over previous
//
#include <hip/hip_runtime.h>
#include <hip/hip_bf16.h>

#define N_TOK   2048
#define DIM     1024
#define HEADS   16
#define DH      64
#define WBLK    32
#define NSEL    8
#define CD      4096

typedef __hip_bfloat16 bf16;
typedef __attribute__((ext_vector_type(8))) short short8;
typedef __attribute__((ext_vector_type(4))) float f32x4;

// ================= async global->LDS (16B per lane) =================
__device__ __forceinline__ void gll16(const void* g, void* l) {
    __builtin_amdgcn_global_load_lds((const __attribute__((address_space(1))) void*)g,
                                     (__attribute__((address_space(3))) void*)l, 16, 0, 0);
}

// ================= MFMA GEMM: C = act(A@B + bias) =================
// BM=64, BN=64, BK=32; 4 waves 2x2, wave tile 32x32. 3-buffer counted-vmcnt pipeline.
// A: bf16 splits [M][K]; B: TRANSPOSED bf16 splits [N][K].
// PAIRS: 1 ; 3 = split2 3-term ; 4 = exact split2^2 ; 6 = split3.
// OUT: 0 = f32 C ; 3 = f32 C + split2 C0,C1 ;
//      5 = f32 C + permuted cmat split2 (pe added) ; 6 = f32 C + permuted cmat single ;
//      7 = split2 C0,C1 + fused-RoPE bf16 (0.125x) into (bf16*)C   [q path]
//      8 = permuted cmat split2 (pe) + fused-RoPE bf16 into (bf16*)C [k path]
template<int PAIRS, int OUT>
__global__ __launch_bounds__(256, 2) void gemm_mfma(
    const bf16* __restrict__ a0, const bf16* __restrict__ a1, const bf16* __restrict__ a2,
    const bf16* __restrict__ b0, const bf16* __restrict__ b1, const bf16* __restrict__ b2,
    const float* __restrict__ bias, float* __restrict__ C,
    bf16* __restrict__ C0, bf16* __restrict__ C1,
    int M, int N, int K, int act, const float* __restrict__ pe,
    const float* __restrict__ fcp)
{
    constexpr int NS = (PAIRS == 6) ? 3 : ((PAIRS >= 3) ? 2 : 1);
    __shared__ __align__(16) bf16 As[3][NS][64][32];
    __shared__ __align__(16) bf16 Bs[3][NS][64][32];

    const int tid = threadIdx.x, lane = tid & 63, wid = tid >> 6;
    const int wr = wid >> 1, wc = wid & 1;
    const int row0 = blockIdx.y * 64, col0 = blockIdx.x * 64;

    const bf16* ap[3] = {a0, a1, a2};
    const bf16* bp[3] = {b0, b1, b2};

    f32x4 acc[2][2];
    #pragma unroll
    for (int mi = 0; mi < 2; ++mi)
        #pragma unroll
        for (int ni = 0; ni < 2; ++ni) acc[mi][ni] = (f32x4){0.f, 0.f, 0.f, 0.f};

    const int lr = lane >> 2;
    const int lc = (((lane & 3) ^ ((lane >> 3) & 3))) * 8;
    const int fo = (((lane >> 4) ^ ((lane >> 1) & 3))) * 8;

    constexpr int pa[6] = {0, 0, 1, 1, 0, 2};
    constexpr int pb[6] = {0, 1, 0, 1, 2, 0};

    auto stage = [&](int buf, int t) {
        const int k0 = t << 5;
        #pragma unroll
        for (int s = 0; s < NS; ++s) {
            gll16(ap[s] + (size_t)(row0 + wid * 16 + lr) * K + k0 + lc, &As[buf][s][wid * 16][0]);
            gll16(bp[s] + (size_t)(col0 + wid * 16 + lr) * K + k0 + lc, &Bs[buf][s][wid * 16][0]);
        }
    };

    const int nt = K >> 5;
    stage(0, 0);
    if (nt > 1) {
        stage(1, 1);
        asm volatile("s_waitcnt vmcnt(%0)" :: "n"(2 * NS) : "memory");
    } else {
        asm volatile("s_waitcnt vmcnt(0)" ::: "memory");
    }
    __builtin_amdgcn_s_barrier();

    for (int t = 0; t < nt; ++t) {
        const int cur = t % 3;

        short8 af[2][NS], bfr[2][NS];
        #pragma unroll
        for (int mi = 0; mi < 2; ++mi)
            #pragma unroll
            for (int s = 0; s < NS; ++s)
                af[mi][s] = *(const short8*)&As[cur][s][wr * 32 + mi * 16 + (lane & 15)][fo];
        #pragma unroll
        for (int ni = 0; ni < 2; ++ni)
            #pragma unroll
            for (int s = 0; s < NS; ++s)
                bfr[ni][s] = *(const short8*)&Bs[cur][s][wc * 32 + ni * 16 + (lane & 15)][fo];

        if (t + 2 < nt) stage((t + 2) % 3, t + 2);

        #pragma unroll
        for (int mi = 0; mi < 2; ++mi)
            #pragma unroll
            for (int ni = 0; ni < 2; ++ni) {
                f32x4 c = acc[mi][ni];
                #pragma unroll
                for (int p = 0; p < PAIRS; ++p)
                    c = __builtin_amdgcn_mfma_f32_16x16x32_bf16(af[mi][pa[p]], bfr[ni][pb[p]], c, 0, 0, 0);
                acc[mi][ni] = c;
            }

        if (t + 1 < nt) {
            if (t + 2 < nt) asm volatile("s_waitcnt vmcnt(%0)" :: "n"(2 * NS) : "memory");
            else            asm volatile("s_waitcnt vmcnt(0)" ::: "memory");
            __builtin_amdgcn_s_barrier();
        }
    }

    #pragma unroll
    for (int mi = 0; mi < 2; ++mi)
        #pragma unroll
        for (int ni = 0; ni < 2; ++ni)
            #pragma unroll
            for (int r = 0; r < 4; ++r) {
                int row = row0 + wr * 32 + mi * 16 + (lane >> 4) * 4 + r;
                int col = col0 + wc * 32 + ni * 16 + (lane & 15);
                float v = acc[mi][ni][r];
                if (bias) v += bias[col];
                if (act == 1) v = fmaxf(v, 0.f);
                if (OUT == 0 || OUT == 3 || OUT == 5 || OUT == 6) C[(size_t)row * N + col] = v;
                if (OUT == 3 || OUT == 7) {
                    bf16 hh = __float2bfloat16(v);
                    C0[(size_t)row * N + col] = hh;
                    C1[(size_t)row * N + col] = __float2bfloat16(v - __bfloat162float(hh));
                }
                if (OUT == 5 || OUT == 6 || OUT == 8) {
                    int w_ = row >> 6, pos = row & 63, hh_ = col >> 6, d_ = col & 63;
                    float xx = v + pe[(size_t)((pos << 4) + hh_) * 64 + d_];
                    size_t ci = ((size_t)((w_ << 4) + hh_) << 12) + (pos << 6) + d_;
                    bf16 bb = __float2bfloat16(xx);
                    C0[ci] = bb;
                    if (OUT == 5 || OUT == 8) C1[ci] = __float2bfloat16(xx - __bfloat162float(bb));
                }
                if (OUT == 7 || OUT == 8) {
                    // fused RoPE: lane^1 holds the partner element (col^1) of the pair
                    int p_ = (col & 63) >> 1;
                    float c_ = fcp[((size_t)row * 32 + p_) * 2];
                    float s_ = fcp[((size_t)row * 32 + p_) * 2 + 1];
                    float partner = __shfl_xor(v, 1);
                    float roped = (col & 1) ? (partner * s_ + v * c_) : (v * c_ - partner * s_);
                    bf16* outb = (bf16*)C;
                    outb[(size_t)row * N + col] =
                        __float2bfloat16(OUT == 7 ? 0.125f * roped : roped);
                }
            }
}

// ================= big-tile split-K GEMM for compress L1 =================
// BM=128, BN=128, BK=32; 4 waves 2x2, wave tile 64x64 (acc 4x4); KC=4 via blockIdx.z.
// 2-buffer drain schedule (LDS 64KB @ NS=2 -> 2 blocks/CU). R17 config: measured 893 TF
// (the ~900 TF ceiling of this 2-barrier structure); 4 rewrite attempts all regressed.
template<int PAIRS>
__global__ __launch_bounds__(256, 2) void gemm_bigk(
    const bf16* __restrict__ a0, const bf16* __restrict__ a1,
    const bf16* __restrict__ b0, const bf16* __restrict__ b1,
    float* __restrict__ part, int M, int N, int K)
{
    constexpr int NS = (PAIRS >= 3) ? 2 : 1;
    __shared__ __align__(16) bf16 As[2][NS][128][32];
    __shared__ __align__(16) bf16 Bs[2][NS][128][32];

    const int tid = threadIdx.x, lane = tid & 63, wid = tid >> 6;
    const int wr = wid >> 1, wc = wid & 1;
    const int row0 = blockIdx.y * 128, col0 = blockIdx.x * 128;
    const int kchunk = K >> 2;
    const int kbase = blockIdx.z * kchunk;

    const bf16* ap[2] = {a0, a1};
    const bf16* bp[2] = {b0, b1};

    f32x4 acc[4][4];
    #pragma unroll
    for (int mi = 0; mi < 4; ++mi)
        #pragma unroll
        for (int ni = 0; ni < 4; ++ni) acc[mi][ni] = (f32x4){0.f, 0.f, 0.f, 0.f};

    const int lr = lane >> 2;
    const int lc = (((lane & 3) ^ ((lane >> 3) & 3))) * 8;
    const int fo = (((lane >> 4) ^ ((lane >> 1) & 3))) * 8;

    constexpr int pa[3] = {0, 0, 1};
    constexpr int pb[3] = {0, 1, 0};

    auto stage = [&](int buf, int t) {
        const int k0 = kbase + (t << 5);
        #pragma unroll
        for (int s = 0; s < NS; ++s) {
            gll16(ap[s] + (size_t)(row0 + wid * 32 + lr) * K + k0 + lc,      &As[buf][s][wid * 32][0]);
            gll16(ap[s] + (size_t)(row0 + wid * 32 + 16 + lr) * K + k0 + lc, &As[buf][s][wid * 32 + 16][0]);
            gll16(bp[s] + (size_t)(col0 + wid * 32 + lr) * K + k0 + lc,      &Bs[buf][s][wid * 32][0]);
            gll16(bp[s] + (size_t)(col0 + wid * 32 + 16 + lr) * K + k0 + lc, &Bs[buf][s][wid * 32 + 16][0]);
        }
    };

    const int nt = kchunk >> 5;
    stage(0, 0);
    __syncthreads();

    for (int t = 0; t < nt; ++t) {
        const int cur = t & 1;
        if (t + 1 < nt) stage(cur ^ 1, t + 1);

        short8 af[4][NS], bfr[4][NS];
        #pragma unroll
        for (int mi = 0; mi < 4; ++mi)
            #pragma unroll
            for (int s = 0; s < NS; ++s)
                af[mi][s] = *(const short8*)&As[cur][s][wr * 64 + mi * 16 + (lane & 15)][fo];
        #pragma unroll
        for (int ni = 0; ni < 4; ++ni)
            #pragma unroll
            for (int s = 0; s < NS; ++s)
                bfr[ni][s] = *(const short8*)&Bs[cur][s][wc * 64 + ni * 16 + (lane & 15)][fo];

        #pragma unroll
        for (int mi = 0; mi < 4; ++mi)
            #pragma unroll
            for (int ni = 0; ni < 4; ++ni) {
                f32x4 c = acc[mi][ni];
                #pragma unroll
                for (int p = 0; p < PAIRS; ++p)
                    c = __builtin_amdgcn_mfma_f32_16x16x32_bf16(af[mi][pa[p]], bfr[ni][pb[p]], c, 0, 0, 0);
                acc[mi][ni] = c;
            }
        __syncthreads();
    }

    #pragma unroll
    for (int mi = 0; mi < 4; ++mi)
        #pragma unroll
        for (int ni = 0; ni < 4; ++ni)
            #pragma unroll
            for (int r = 0; r < 4; ++r) {
                int row = row0 + wr * 64 + mi * 16 + (lane >> 4) * 4 + r;
                int col = col0 + wc * 64 + ni * 16 + (lane & 15);
                part[((size_t)blockIdx.z * M + row) * N + col] = acc[mi][ni][r];
            }
}

// reduce 4 split-K partials + bias + relu -> split2 bf16 h
__global__ void kredh(const float* __restrict__ part, const float* __restrict__ bias,
                      bf16* __restrict__ h0, bf16* __restrict__ h1) {
    int i = blockIdx.x * 256 + threadIdx.x;
    const size_t stride = (size_t)512 * CD;
    float s = part[i] + part[stride + i] + part[2 * stride + i] + part[3 * stride + i]
            + bias[i & (CD - 1)];
    s = fmaxf(s, 0.f);
    bf16 hh = __float2bfloat16(s);
    h0[i] = hh;
    h1[i] = __float2bfloat16(s - __bfloat162float(hh));
}

// ================= split-K skinny MFMA GEMM (3-buffer pipeline) =================
template<int KC>
__global__ __launch_bounds__(256, 2) void sk_gemm(
    const bf16* __restrict__ a0, const bf16* __restrict__ a1,
    const bf16* __restrict__ b0, const bf16* __restrict__ b1,
    float* __restrict__ part, int M, int K)
{
    __shared__ __align__(16) bf16 As[3][2][64][32];
    __shared__ __align__(16) bf16 Bs[3][2][64][32];
    const int tid = threadIdx.x, lane = tid & 63, wid = tid >> 6;
    const int wr = wid >> 1, wc = wid & 1;
    const int row0 = blockIdx.x * 64;
    const int kchunk = K / KC;
    const int kbase = blockIdx.y * kchunk;
    const bf16* ap[2] = {a0, a1};
    const bf16* bp[2] = {b0, b1};
    const int lr = lane >> 2;
    const int lc = (((lane & 3) ^ ((lane >> 3) & 3))) * 8;
    const int fo = (((lane >> 4) ^ ((lane >> 1) & 3))) * 8;

    f32x4 acc[2][2];
    #pragma unroll
    for (int mi = 0; mi < 2; ++mi)
        #pragma unroll
        for (int ni = 0; ni < 2; ++ni) acc[mi][ni] = (f32x4){0.f, 0.f, 0.f, 0.f};

    auto stage = [&](int buf, int t) {
        const int k0 = kbase + (t << 5);
        #pragma unroll
        for (int s = 0; s < 2; ++s) {
            gll16(ap[s] + (size_t)(row0 + wid * 16 + lr) * K + k0 + lc, &As[buf][s][wid * 16][0]);
            gll16(bp[s] + (size_t)(wid * 16 + lr) * K + k0 + lc,        &Bs[buf][s][wid * 16][0]);
        }
    };

    const int nt = kchunk >> 5;
    stage(0, 0);
    if (nt > 1) {
        stage(1, 1);
        asm volatile("s_waitcnt vmcnt(4)" ::: "memory");
    } else {
        asm volatile("s_waitcnt vmcnt(0)" ::: "memory");
    }
    __builtin_amdgcn_s_barrier();

    for (int t = 0; t < nt; ++t) {
        const int cur = t % 3;
        short8 af[2][2], bfr[2][2];
        #pragma unroll
        for (int mi = 0; mi < 2; ++mi)
            #pragma unroll
            for (int s = 0; s < 2; ++s)
                af[mi][s] = *(const short8*)&As[cur][s][wr * 32 + mi * 16 + (lane & 15)][fo];
        #pragma unroll
        for (int ni = 0; ni < 2; ++ni)
            #pragma unroll
            for (int s = 0; s < 2; ++s)
                bfr[ni][s] = *(const short8*)&Bs[cur][s][wc * 32 + ni * 16 + (lane & 15)][fo];

        if (t + 2 < nt) stage((t + 2) % 3, t + 2);

        #pragma unroll
        for (int mi = 0; mi < 2; ++mi)
            #pragma unroll
            for (int ni = 0; ni < 2; ++ni) {
                f32x4 c = acc[mi][ni];
                c = __builtin_amdgcn_mfma_f32_16x16x32_bf16(af[mi][0], bfr[ni][0], c, 0, 0, 0);
                c = __builtin_amdgcn_mfma_f32_16x16x32_bf16(af[mi][0], bfr[ni][1], c, 0, 0, 0);
                c = __builtin_amdgcn_mfma_f32_16x16x32_bf16(af[mi][1], bfr[ni][0], c, 0, 0, 0);
                acc[mi][ni] = c;
            }

        if (t + 1 < nt) {
            if (t + 2 < nt) asm volatile("s_waitcnt vmcnt(4)" ::: "memory");
            else            asm volatile("s_waitcnt vmcnt(0)" ::: "memory");
            __builtin_amdgcn_s_barrier();
        }
    }

    #pragma unroll
    for (int mi = 0; mi < 2; ++mi)
        #pragma unroll
        for (int ni = 0; ni < 2; ++ni)
            #pragma unroll
            for (int r = 0; r < 4; ++r) {
                int row = row0 + wr * 32 + mi * 16 + (lane >> 4) * 4 + r;
                int col = wc * 32 + ni * 16 + (lane & 15);
                part[((size_t)blockIdx.y * M + row) * 64 + col] = acc[mi][ni][r];
            }
}

// skred: reduce split-K partials; optionally emit split2 bf16 of the result
__global__ void skred(const float* __restrict__ part, const float* __restrict__ bias,
                      float* __restrict__ C, bf16* __restrict__ C0, bf16* __restrict__ C1,
                      int M, int KC) {
    int i = blockIdx.x * 256 + threadIdx.x;
    if (i >= M * 64) return;
    float s = bias ? bias[i & 63] : 0.f;
    for (int kc = 0; kc < KC; ++kc) s += part[(size_t)kc * M * 64 + i];
    C[i] = s;
    if (C0) {
        bf16 hh = __float2bfloat16(s);
        C0[i] = hh;
        C1[i] = __float2bfloat16(s - __bfloat162float(hh));
    }
}

// ================= cscore GEMM via MFMA (also zeroes counts) =================
__global__ __launch_bounds__(256) void cscore_gemm(const bf16* __restrict__ qs0,
                                                   const bf16* __restrict__ qs1,
                                                   const bf16* __restrict__ ck0,
                                                   const bf16* __restrict__ ck1,
                                                   float* __restrict__ Sc,
                                                   int* __restrict__ counts) {
    if (blockIdx.x == 0 && blockIdx.y == 0) {
        counts[threadIdx.x] = 0;
        counts[threadIdx.x + 256] = 0;
    }
    int h = blockIdx.y;
    int wid = threadIdx.x >> 6, lane = threadIdx.x & 63;
    int q0 = blockIdx.x * 128 + wid * 32;
    const int lr = lane & 15, hc = lane >> 4;

    f32x4 acc[2][2];
    #pragma unroll
    for (int a = 0; a < 2; ++a)
        #pragma unroll
        for (int b = 0; b < 2; ++b) acc[a][b] = (f32x4){0.f, 0.f, 0.f, 0.f};

    short8 av[2][2][2], bv[2][2][2];
    #pragma unroll
    for (int qs_ = 0; qs_ < 2; ++qs_)
        #pragma unroll
        for (int ks = 0; ks < 2; ++ks) {
            size_t off = ((size_t)(q0 + qs_ * 16 + lr) << 10) + (h << 6) + ks * 32 + hc * 8;
            av[qs_][ks][0] = *(const short8*)(qs0 + off);
            av[qs_][ks][1] = *(const short8*)(qs1 + off);
        }
    #pragma unroll
    for (int ws = 0; ws < 2; ++ws)
        #pragma unroll
        for (int ks = 0; ks < 2; ++ks) {
            size_t off = ((size_t)(((ws * 16 + lr) << 4) + h)) * 64 + ks * 32 + hc * 8;
            bv[ws][ks][0] = *(const short8*)(ck0 + off);
            bv[ws][ks][1] = *(const short8*)(ck1 + off);
        }
    #pragma unroll
    for (int qs_ = 0; qs_ < 2; ++qs_)
        #pragma unroll
        for (int ws = 0; ws < 2; ++ws) {
            f32x4 c = acc[qs_][ws];
            #pragma unroll
            for (int ks = 0; ks < 2; ++ks) {
                c = __builtin_amdgcn_mfma_f32_16x16x32_bf16(av[qs_][ks][0], bv[ws][ks][0], c, 0, 0, 0);
                c = __builtin_amdgcn_mfma_f32_16x16x32_bf16(av[qs_][ks][0], bv[ws][ks][1], c, 0, 0, 0);
                c = __builtin_amdgcn_mfma_f32_16x16x32_bf16(av[qs_][ks][1], bv[ws][ks][0], c, 0, 0, 0);
            }
            acc[qs_][ws] = c;
        }
    #pragma unroll
    for (int qs_ = 0; qs_ < 2; ++qs_)
        #pragma unroll
        for (int ws = 0; ws < 2; ++ws)
            #pragma unroll
            for (int r = 0; r < 4; ++r) {
                int q = q0 + qs_ * 16 + hc * 4 + r;
                int w = ws * 16 + lr;
                Sc[((size_t)(h << 11) + q) * 32 + w] = acc[qs_][ws][r] * 0.125f;
            }
}

// ================= softmax + rank-based top-8 + compressed PV =================
__global__ __launch_bounds__(256) void ctopk_pv(const float* __restrict__ Sc,
                                                const float* __restrict__ cv,
                                                float* __restrict__ comp,
                                                int* __restrict__ idxb) {
    int item = blockIdx.x * 4 + (threadIdx.x >> 6);
    int lane = threadIdx.x & 63;
    int h = item >> 11, qpos = item & 2047;
    float logit = (lane < 32) ? Sc[(size_t)item * 32 + lane] : -1e30f;
    float m = logit;
    #pragma unroll
    for (int o = 32; o; o >>= 1) m = fmaxf(m, __shfl_xor(m, o));
    float e = (lane < 32) ? expf(logit - m) : 0.f;
    float s = e;
    #pragma unroll
    for (int o = 32; o; o >>= 1) s += __shfl_xor(s, o);
    float inv = 1.f / s;
    float acc = 0.f;
    #pragma unroll 8
    for (int w = 0; w < WBLK; ++w) {
        float pw = __shfl(e, w) * inv;
        acc += pw * cv[(size_t)((w << 4) + h) * 64 + lane];
    }
    comp[(size_t)(qpos << 10) + (h << 6) + lane] = acc;
    int rank = 0;
    #pragma unroll 8
    for (int j = 0; j < WBLK; ++j) {
        float lj = __shfl(logit, j);
        rank += (lj > logit || (lj == logit && j < lane)) ? 1 : 0;
    }
    if (lane < 32 && rank < NSEL) idxb[item * NSEL + rank] = lane;
}

// ================= gate: sigmoid(x @ Wc + bc) =================
__global__ __launch_bounds__(256) void gate_gemm(const float* __restrict__ x,
                                                 const float* __restrict__ Wc,
                                                 const float* __restrict__ bc,
                                                 float* __restrict__ gate) {
    __shared__ float xr[1024];
    __shared__ float part[8][32];
    int row = blockIdx.x;
    #pragma unroll
    for (int i = 0; i < 4; ++i)
        xr[threadIdx.x + i * 256] = x[(size_t)row * 1024 + threadIdx.x + i * 256];
    __syncthreads();
    int c = threadIdx.x & 31, sl = threadIdx.x >> 5;
    float acc = 0.f;
    for (int k = sl; k < 1024; k += 8) acc += xr[k] * Wc[k * 32 + c];
    part[sl][c] = acc;
    __syncthreads();
    if (sl == 0) {
        float v = bc[c];
        #pragma unroll
        for (int j = 0; j < 8; ++j) v += part[j][c];
        gate[(size_t)row * 32 + c] = 1.f / (1.f + expf(-v));
    }
}

// ================= transpose + split =================
template<int NS>
__global__ __launch_bounds__(256) void tsplit(const float* __restrict__ B,
                                              bf16* __restrict__ t0, bf16* __restrict__ t1,
                                              bf16* __restrict__ t2, int K, int N) {
    __shared__ float tile[32][33];
    int tx = threadIdx.x & 31, ty = threadIdx.x >> 5;
    int bx = blockIdx.x, by = blockIdx.y;
    #pragma unroll
    for (int i = 0; i < 4; ++i)
        tile[ty + i * 8][tx] = B[(size_t)(by * 32 + ty + i * 8) * N + bx * 32 + tx];
    __syncthreads();
    #pragma unroll
    for (int i = 0; i < 4; ++i) {
        int nn = bx * 32 + ty + i * 8;
        int kk = by * 32 + tx;
        float x = tile[tx][ty + i * 8];
        bf16 h = __float2bfloat16(x);
        t0[(size_t)nn * K + kk] = h;
        if (NS >= 2) {
            float r1 = x - __bfloat162float(h);
            bf16 m = __float2bfloat16(r1);
            t1[(size_t)nn * K + kk] = m;
            if (NS == 3) t2[(size_t)nn * K + kk] = __float2bfloat16(r1 - __bfloat162float(m));
        }
    }
}

// ================= elementwise split =================
__global__ void split2_k(const float* __restrict__ s, bf16* __restrict__ d0,
                         bf16* __restrict__ d1, int n) {
    int i = blockIdx.x * 256 + threadIdx.x;
    if (i >= n) return;
    float x = s[i];
    bf16 h = __float2bfloat16(x); d0[i] = h;
    d1[i] = __float2bfloat16(x - __bfloat162float(h));
}

// ================= fallback helpers =================
__global__ void build_cmat(const float* __restrict__ kv, const float* __restrict__ pe,
                           float* __restrict__ cmat) {
    int i = blockIdx.x * 256 + threadIdx.x;
    int r = i >> 12, c = i & 4095;
    int w = r >> 4, h = r & 15;
    int pos = c >> 6, d = c & 63;
    cmat[i] = kv[(size_t)((w * 64 + pos) << 10) + (h << 6) + d] +
              pe[(size_t)((pos << 4) + h) * 64 + d];
}

__global__ __launch_bounds__(256) void gemm_skinny64(const float* __restrict__ A,
                                                     const float* __restrict__ B,
                                                     const float* __restrict__ bias,
                                                     float* __restrict__ C, int K) {
    __shared__ float Arow[4096];
    __shared__ float part[4][64];
    int row = blockIdx.x;
    for (int i = threadIdx.x; i < K; i += 256) Arow[i] = A[(size_t)row * K + i];
    __syncthreads();
    int c = threadIdx.x & 63, sl = threadIdx.x >> 6;
    float acc = 0.f;
    for (int k = sl; k < K; k += 4) acc += Arow[k] * B[(size_t)k * 64 + c];
    part[sl][c] = acc;
    __syncthreads();
    if (sl == 0) {
        float v = part[0][c] + part[1][c] + part[2][c] + part[3][c];
        if (bias) v += bias[c];
        C[(size_t)row * 64 + c] = v;
    }
}

__global__ __launch_bounds__(256) void gemm_f32(const float* __restrict__ A,
                                                const float* __restrict__ B,
                                                const float* __restrict__ bias,
                                                float* __restrict__ C,
                                                int M, int N, int K, int act) {
    __shared__ float As[16][65];
    __shared__ float Bs[16][65];
    const int tid  = threadIdx.x;
    const int row0 = blockIdx.y * 64;
    const int col0 = blockIdx.x * 64;
    const int tm = tid >> 4;
    const int tn = tid & 15;

    float acc[4][4];
    #pragma unroll
    for (int i = 0; i < 4; ++i)
        #pragma unroll
        for (int j = 0; j < 4; ++j) acc[i][j] = 0.f;

    const int ar  = tid >> 2;
    const int akq = (tid & 3) << 2;

    for (int k0 = 0; k0 < K; k0 += 16) {
        float4 a4 = make_float4(0.f, 0.f, 0.f, 0.f);
        if (row0 + ar < M)
            a4 = *reinterpret_cast<const float4*>(&A[(size_t)(row0 + ar) * K + k0 + akq]);
        As[akq + 0][ar] = a4.x; As[akq + 1][ar] = a4.y;
        As[akq + 2][ar] = a4.z; As[akq + 3][ar] = a4.w;
        #pragma unroll
        for (int it = 0; it < 4; ++it) {
            int idx = tid + it * 256;
            int kr = idx >> 6, c = idx & 63;
            float bv = 0.f;
            if (col0 + c < N) bv = B[(size_t)(k0 + kr) * N + col0 + c];
            Bs[kr][c] = bv;
        }
        __syncthreads();
        #pragma unroll
        for (int kk = 0; kk < 16; ++kk) {
            float a0 = As[kk][tm * 4 + 0], a1 = As[kk][tm * 4 + 1];
            float a2 = As[kk][tm * 4 + 2], a3 = As[kk][tm * 4 + 3];
            float b0v = Bs[kk][tn * 4 + 0], b1v = Bs[kk][tn * 4 + 1];
            float b2v = Bs[kk][tn * 4 + 2], b3v = Bs[kk][tn * 4 + 3];
            acc[0][0] += a0 * b0v; acc[0][1] += a0 * b1v; acc[0][2] += a0 * b2v; acc[0][3] += a0 * b3v;
            acc[1][0] += a1 * b0v; acc[1][1] += a1 * b1v; acc[1][2] += a1 * b2v; acc[1][3] += a1 * b3v;
            acc[2][0] += a2 * b0v; acc[2][1] += a2 * b1v; acc[2][2] += a2 * b2v; acc[2][3] += a2 * b3v;
            acc[3][0] += a3 * b0v; acc[3][1] += a3 * b1v; acc[3][2] += a3 * b2v; acc[3][3] += a3 * b3v;
        }
        __syncthreads();
    }

    #pragma unroll
    for (int i = 0; i < 4; ++i) {
        int r = row0 + tm * 4 + i;
        if (r >= M) continue;
        #pragma unroll
        for (int j = 0; j < 4; ++j) {
            int cc = col0 + tn * 4 + j;
            if (cc >= N) continue;
            float vv = acc[i][j];
            if (bias) vv += bias[cc];
            if (act == 1) vv = fmaxf(vv, 0.f);
            else if (act == 2) vv = 1.f / (1.f + expf(-vv));
            C[(size_t)r * N + cc] = vv;
        }
    }
}

__global__ __launch_bounds__(256) void cscore_topk(const float* __restrict__ q,
                                                   const float* __restrict__ ck,
                                                   float* __restrict__ cprob,
                                                   int* __restrict__ idxb) {
    int item = blockIdx.x * 4 + (threadIdx.x >> 6);
    int lane = threadIdx.x & 63;
    int h = item >> 11;
    int qpos = item & 2047;
    float qv = q[(size_t)(qpos << 10) + (h << 6) + lane];
    float logit = -1e30f;
    const float scale = 0.125f;
    for (int w = 0; w < WBLK; ++w) {
        float p = qv * ck[(size_t)((w << 4) + h) * 64 + lane];
        #pragma unroll
        for (int o = 32; o; o >>= 1) p += __shfl_xor(p, o);
        if (lane == w) logit = p * scale;
    }
    float m = logit;
    #pragma unroll
    for (int o = 32; o; o >>= 1) m = fmaxf(m, __shfl_xor(m, o));
    float e = (lane < 32) ? expf(logit - m) : 0.f;
    float s = e;
    #pragma unroll
    for (int o = 32; o; o >>= 1) s += __shfl_xor(s, o);
    if (lane < 32) cprob[(size_t)item * WBLK + lane] = e / s;
    float vcur = logit;
    for (int t = 0; t < NSEL; ++t) {
        float bm = vcur; int bi = lane;
        #pragma unroll
        for (int o = 32; o; o >>= 1) {
            float om = __shfl_xor(bm, o); int oi = __shfl_xor(bi, o);
            if (om > bm || (om == bm && oi < bi)) { bm = om; bi = oi; }
        }
        if (lane == 0) idxb[item * NSEL + t] = bi;
        if (lane == bi) vcur = -1e30f;
    }
}
__global__ void compressed_pv(const float* __restrict__ cprob, const float* __restrict__ cv,
                              float* __restrict__ comp) {
    int i = blockIdx.x * 256 + threadIdx.x;
    int qpos = i >> 10; int hd = i & 1023; int h = hd >> 6; int d = hd & 63;
    const float* pr = &cprob[(size_t)(h * N_TOK + qpos) * WBLK];
    float acc = 0.f;
    #pragma unroll
    for (int w = 0; w < WBLK; ++w) acc += pr[w] * cv[(size_t)((w << 4) + h) * 64 + d];
    comp[i] = acc;
}

__global__ void rope_ip(float* __restrict__ q, float* __restrict__ k,
                        const float* __restrict__ fc) {
    int i = blockIdx.x * 256 + threadIdx.x;
    int n = i >> 9; int hp = i & 511; int h = hp >> 5; int p = hp & 31;
    float c = fc[(size_t)(n * 32 + p) * 2];
    float s = fc[(size_t)(n * 32 + p) * 2 + 1];
    size_t base = (size_t)(n << 10) + (h << 6) + (p << 1);
    float qr = q[base], qi = q[base + 1];
    q[base] = qr * c - qi * s; q[base + 1] = qr * s + qi * c;
    float kr = k[base], ki = k[base + 1];
    k[base] = kr * c - ki * s; k[base + 1] = kr * s + ki * c;
}

// ================= coalesced V transpose =================
__global__ __launch_bounds__(256) void convert_vT(const float* __restrict__ v,
                                                  bf16* __restrict__ vbT) {
    __shared__ float tile[64][65];
    int h = blockIdx.x;
    int n0 = blockIdx.y * 64;
    int tx = threadIdx.x & 63, ty = threadIdx.x >> 6;
    #pragma unroll
    for (int i = 0; i < 16; ++i)
        tile[ty + 4 * i][tx] = v[(size_t)(n0 + ty + 4 * i) * 1024 + (h << 6) + tx];
    __syncthreads();
    #pragma unroll
    for (int i = 0; i < 16; ++i) {
        int d = ty + 4 * i;
        vbT[((size_t)(h << 6) + d) * 2048 + n0 + tx] = __float2bfloat16(tile[tx][d]);
    }
}

// ================= hierarchical build_lists =================
__global__ __launch_bounds__(256) void build_lists(const int* __restrict__ idxb,
                                                   int* __restrict__ counts,
                                                   int* __restrict__ lists) {
    __shared__ int lcnt[32];
    __shared__ int gbase[32];
    int h = blockIdx.x >> 3;
    int q = ((blockIdx.x & 7) << 8) + threadIdx.x;
    if (threadIdx.x < 32) lcnt[threadIdx.x] = 0;
    __syncthreads();
    int item = (h << 11) + q;
    int wv[NSEL], lo[NSEL];
    #pragma unroll
    for (int t = 0; t < NSEL; ++t) {
        wv[t] = idxb[item * NSEL + t];
        lo[t] = atomicAdd(&lcnt[wv[t]], 1);
    }
    __syncthreads();
    if (threadIdx.x < 32)
        gbase[threadIdx.x] = atomicAdd(&counts[(h << 5) + threadIdx.x], lcnt[threadIdx.x]);
    __syncthreads();
    #pragma unroll
    for (int t = 0; t < NSEL; ++t) {
        int g = (h << 5) + wv[t];
        lists[g * 2048 + gbase[wv[t]] + lo[t]] = (q << 3) | t;
    }
}

__global__ void convert_qkv(const float* __restrict__ q, const float* __restrict__ k,
                            const float* __restrict__ v, bf16* __restrict__ qb,
                            bf16* __restrict__ kb, bf16* __restrict__ vbT) {
    int i = blockIdx.x * 256 + threadIdx.x;
    qb[i] = __float2bfloat16(0.125f * q[i]);
    kb[i] = __float2bfloat16(k[i]);
    int h = i >> 17, d = (i >> 11) & 63, n = i & 2047;
    vbT[i] = __float2bfloat16(v[(size_t)(n << 10) + (h << 6) + d]);
}

__global__ __launch_bounds__(64) void sel_scores(const bf16* __restrict__ qb,
                                                 const bf16* __restrict__ kb,
                                                 const int* __restrict__ counts,
                                                 const int* __restrict__ lists,
                                                 float* __restrict__ S) {
    int g = blockIdx.x;
    int cnt = counts[g];
    int tile = blockIdx.y;
    if (tile * 32 >= cnt) return;
    int h = g >> 5, w = g & 31;
    int lane = threadIdx.x;
    __shared__ int qt[32];
    __shared__ float st[32][66];
    int nrow = cnt - tile * 32; if (nrow > 32) nrow = 32;
    if (lane < 32) qt[lane] = lists[g * 2048 + tile * 32 + (lane < nrow ? lane : nrow - 1)];
    __syncthreads();
    int lr = lane & 15, hc = lane >> 4;

    f32x4 acc[2][4];
    #pragma unroll
    for (int m = 0; m < 2; ++m)
        #pragma unroll
        for (int gk = 0; gk < 4; ++gk) acc[m][gk] = (f32x4){0.f, 0.f, 0.f, 0.f};

    short8 a[2][2], b[4][2];
    #pragma unroll
    for (int m = 0; m < 2; ++m) {
        int qq = qt[m * 16 + lr] >> 3;
        const bf16* ar = qb + ((size_t)qq << 10) + (h << 6) + hc * 8;
        a[m][0] = *(const short8*)ar;
        a[m][1] = *(const short8*)(ar + 32);
    }
    #pragma unroll
    for (int gk = 0; gk < 4; ++gk) {
        const bf16* kr = kb + ((size_t)((w << 6) + gk * 16 + lr) << 10) + (h << 6) + hc * 8;
        b[gk][0] = *(const short8*)kr;
        b[gk][1] = *(const short8*)(kr + 32);
    }
    #pragma unroll
    for (int m = 0; m < 2; ++m)
        #pragma unroll
        for (int gk = 0; gk < 4; ++gk) {
            acc[m][gk] = __builtin_amdgcn_mfma_f32_16x16x32_bf16(a[m][0], b[gk][0], acc[m][gk], 0, 0, 0);
            acc[m][gk] = __builtin_amdgcn_mfma_f32_16x16x32_bf16(a[m][1], b[gk][1], acc[m][gk], 0, 0, 0);
        }
    #pragma unroll
    for (int m = 0; m < 2; ++m)
        #pragma unroll
        for (int gk = 0; gk < 4; ++gk)
            #pragma unroll
            for (int r = 0; r < 4; ++r)
                st[m * 16 + hc * 4 + r][gk * 16 + lr] = acc[m][gk][r];
    __syncthreads();
    for (int rr = 0; rr < nrow; ++rr) {
        int e = qt[rr]; int qq = e >> 3, t = e & 7;
        S[((size_t)((h << 11) + qq) << 9) + (t << 6) + lane] = st[rr][lane];
    }
}

__global__ __launch_bounds__(256) void sel_softmax(const float* __restrict__ S,
                                                   bf16* __restrict__ P) {
    int item = blockIdx.x * 4 + (threadIdx.x >> 6);
    int lane = threadIdx.x & 63;
    const float* row = S + ((size_t)item << 9);
    float v[8]; float m = -1e30f;
    #pragma unroll
    for (int j = 0; j < 8; ++j) { v[j] = row[(j << 6) + lane]; m = fmaxf(m, v[j]); }
    #pragma unroll
    for (int o = 32; o; o >>= 1) m = fmaxf(m, __shfl_xor(m, o));
    float s = 0.f;
    #pragma unroll
    for (int j = 0; j < 8; ++j) { v[j] = expf(v[j] - m); s += v[j]; }
    #pragma unroll
    for (int o = 32; o; o >>= 1) s += __shfl_xor(s, o);
    float inv = 1.f / s;
    #pragma unroll
    for (int j = 0; j < 8; ++j)
        P[((size_t)item << 9) + (j << 6) + lane] = __float2bfloat16(v[j] * inv);
}

// Phase D: gathered PV GEMM -> Opart[item][t][64] in bf16
__global__ __launch_bounds__(64) void sel_pv(const bf16* __restrict__ P,
                                             const bf16* __restrict__ vbT,
                                             const int* __restrict__ counts,
                                             const int* __restrict__ lists,
                                             bf16* __restrict__ Opart) {
    int g = blockIdx.x;
    int cnt = counts[g];
    int tile = blockIdx.y;
    if (tile * 32 >= cnt) return;
    int h = g >> 5, w = g & 31;
    int lane = threadIdx.x;
    __shared__ int qt[32];
    __shared__ float st[32][66];
    int nrow = cnt - tile * 32; if (nrow > 32) nrow = 32;
    if (lane < 32) qt[lane] = lists[g * 2048 + tile * 32 + (lane < nrow ? lane : nrow - 1)];
    __syncthreads();
    int lr = lane & 15, hc = lane >> 4;

    f32x4 acc[2][4];
    #pragma unroll
    for (int m = 0; m < 2; ++m)
        #pragma unroll
        for (int dg = 0; dg < 4; ++dg) acc[m][dg] = (f32x4){0.f, 0.f, 0.f, 0.f};

    short8 a[2][2], b[4][2];
    #pragma unroll
    for (int m = 0; m < 2; ++m) {
        int e = qt[m * 16 + lr]; int qq = e >> 3, t = e & 7;
        const bf16* pr = P + ((size_t)((h << 11) + qq) << 9) + (t << 6) + hc * 8;
        a[m][0] = *(const short8*)pr;
        a[m][1] = *(const short8*)(pr + 32);
    }
    #pragma unroll
    for (int dg = 0; dg < 4; ++dg) {
        const bf16* vr = vbT + ((size_t)((h << 6) + dg * 16 + lr) << 11) + (w << 6) + hc * 8;
        b[dg][0] = *(const short8*)vr;
        b[dg][1] = *(const short8*)(vr + 32);
    }
    #pragma unroll
    for (int m = 0; m < 2; ++m)
        #pragma unroll
        for (int dg = 0; dg < 4; ++dg) {
            acc[m][dg] = __builtin_amdgcn_mfma_f32_16x16x32_bf16(a[m][0], b[dg][0], acc[m][dg], 0, 0, 0);
            acc[m][dg] = __builtin_amdgcn_mfma_f32_16x16x32_bf16(a[m][1], b[dg][1], acc[m][dg], 0, 0, 0);
        }
    #pragma unroll
    for (int m = 0; m < 2; ++m)
        #pragma unroll
        for (int dg = 0; dg < 4; ++dg)
            #pragma unroll
            for (int r = 0; r < 4; ++r)
                st[m * 16 + hc * 4 + r][dg * 16 + lr] = acc[m][dg][r];
    __syncthreads();
    for (int rr = 0; rr < nrow; ++rr) {
        int e = qt[rr]; int qq = e >> 3, t = e & 7;
        Opart[((size_t)((h << 11) + qq) << 9) + (t << 6) + lane] = __float2bfloat16(st[rr][lane]);
    }
}

// Phase E: y = g0*comp + g1*sum_t Opart, emitted directly as split2 bf16
__global__ void sel_combine(const bf16* __restrict__ Opart, const float* __restrict__ comp,
                            const float* __restrict__ gate,
                            bf16* __restrict__ y0, bf16* __restrict__ y1) {
    int i = blockIdx.x * 256 + threadIdx.x;
    int qpos = i >> 10, hd = i & 1023, h = hd >> 6, d = hd & 63;
    size_t base = ((size_t)((h << 11) + qpos) << 9) + d;
    float s = 0.f;
    #pragma unroll
    for (int t = 0; t < 8; ++t) s += __bfloat162float(Opart[base + (t << 6)]);
    float g0 = gate[(size_t)qpos * 32 + h];
    float g1 = gate[(size_t)qpos * 32 + 16 + h];
    float val = g0 * comp[i] + g1 * s;
    bf16 b0 = __float2bfloat16(val);
    y0[i] = b0;
    y1[i] = __float2bfloat16(val - __bfloat162float(b0));
}

// ================= fallback fused selected attention =================
__global__ __launch_bounds__(64) void selected_attn(const float* __restrict__ sq,
                                                    const float* __restrict__ sk,
                                                    const float* __restrict__ v,
                                                    const int* __restrict__ idxb,
                                                    const float* __restrict__ comp,
                                                    const float* __restrict__ gate,
                                                    float* __restrict__ y) {
    __shared__ float tile[64][65];
    __shared__ float sqs[64];
    __shared__ float pls[64];
    int item = blockIdx.x;
    int h = item >> 11, qpos = item & 2047;
    int lane = threadIdx.x;
    sqs[lane] = sq[(size_t)(qpos << 10) + (h << 6) + lane];
    int idx[NSEL];
    #pragma unroll
    for (int t = 0; t < NSEL; ++t) idx[t] = idxb[item * NSEL + t];

    const float scale = 0.125f;
    float sc[NSEL];
    float m = -1e30f;
    for (int t = 0; t < NSEL; ++t) {
        int w = idx[t];
        __syncthreads();
        for (int r = 0; r < 64; ++r)
            tile[r][lane] = sk[(size_t)((w << 6) + r) * 1024 + (h << 6) + lane];
        __syncthreads();
        float acc = 0.f;
        #pragma unroll
        for (int d = 0; d < 64; ++d) acc += sqs[d] * tile[lane][d];
        sc[t] = acc * scale;
        m = fmaxf(m, sc[t]);
    }
    #pragma unroll
    for (int o = 32; o; o >>= 1) m = fmaxf(m, __shfl_xor(m, o));
    float p[NSEL];
    float denom = 0.f;
    #pragma unroll
    for (int t = 0; t < NSEL; ++t) { p[t] = expf(sc[t] - m); denom += p[t]; }
    #pragma unroll
    for (int o = 32; o; o >>= 1) denom += __shfl_xor(denom, o);
    float inv = 1.f / denom;

    float acc = 0.f;
    for (int t = 0; t < NSEL; ++t) {
        int w = idx[t];
        __syncthreads();
        for (int r = 0; r < 64; ++r)
            tile[r][lane] = v[(size_t)((w << 6) + r) * 1024 + (h << 6) + lane];
        pls[lane] = p[t];
        __syncthreads();
        #pragma unroll
        for (int j = 0; j < 64; ++j) acc += pls[j] * tile[j][lane];
    }
    acc *= inv;

    float g0 = gate[(size_t)qpos * 32 + h];
    float g1 = gate[(size_t)qpos * 32 + 16 + h];
    size_t o = (size_t)(qpos << 10) + (h << 6) + lane;
    y[o] = g0 * comp[o] + g1 * acc;
}

extern "C" void kernel_launch(void* const* d_in, const int* in_sizes, int n_in,
                              void* d_out, int out_size, void* d_ws, size_t ws_size,
                              hipStream_t stream) {
    const float* x   = (const float*)d_in[0];
    const float* fc  = (const float*)d_in[1];
    const float* Wq  = (const float*)d_in[2];
    const float* Wk  = (const float*)d_in[3];
    const float* Wv  = (const float*)d_in[4];
    const float* Wo  = (const float*)d_in[5];
    const float* pe  = (const float*)d_in[6];
    const float* kW1 = (const float*)d_in[7];
    const float* kb1 = (const float*)d_in[8];
    const float* kW2 = (const float*)d_in[9];
    const float* kb2 = (const float*)d_in[10];
    const float* vW1 = (const float*)d_in[11];
    const float* vb1 = (const float*)d_in[12];
    const float* vW2 = (const float*)d_in[13];
    const float* vb2 = (const float*)d_in[14];
    const float* Wc  = (const float*)d_in[15];
    const float* bc  = (const float*)d_in[16];
    float* out = (float*)d_out;

    char* base = (char*)d_ws;
    size_t off = 0;
    auto alloc = [&](size_t bytes) -> void* {
        void* r = base + off;
        off += (bytes + 255) & ~(size_t)255;
        return r;
    };
    const size_t E2M = 2097152;   // 2048*1024
    float* q     = (float*)alloc(E2M * 4);
    float* k     = (float*)alloc(E2M * 4);
    float* v     = (float*)alloc(E2M * 4);
    float* gate  = (float*)alloc(N_TOK * 32 * 4);
    float* comp  = (float*)alloc(E2M * 4);
    float* hreg  = (float*)alloc(E2M * 4);     // hosts h0,h1 bf16 splits
    float* y     = (float*)alloc(E2M * 4);     // hosts sk_gemm partials + Sc
    float* ck    = (float*)alloc(512 * 64 * 4);
    float* cv    = (float*)alloc(512 * 64 * 4);
    float* cprob = (float*)alloc((size_t)HEADS * N_TOK * WBLK * 4);
    int*   idxb  = (int*)alloc((size_t)HEADS * N_TOK * NSEL * 4);
    bf16* xs0 = (bf16*)alloc(E2M * 2);
    bf16* xs1 = (bf16*)alloc(E2M * 2);
    bf16* WqT0 = (bf16*)alloc((size_t)DIM * DIM * 2);
    bf16* WqT1 = (bf16*)alloc((size_t)DIM * DIM * 2);
    bf16* WkT0 = (bf16*)alloc((size_t)DIM * DIM * 2);
    bf16* WkT1 = (bf16*)alloc((size_t)DIM * DIM * 2);
    bf16* WvT  = (bf16*)alloc((size_t)DIM * DIM * 2);
    bf16* WoT0 = (bf16*)alloc((size_t)DIM * DIM * 2);
    bf16* WoT1 = (bf16*)alloc((size_t)DIM * DIM * 2);
    bf16* kW1T0 = (bf16*)alloc((size_t)CD * CD * 2);   // later aliased by S/Opart
    bf16* kW1T1 = (bf16*)alloc((size_t)CD * CD * 2);
    bf16* vW1T  = (bf16*)alloc((size_t)CD * CD * 2);
    bf16* kW2T0 = (bf16*)alloc((size_t)64 * CD * 2);
    bf16* kW2T1 = (bf16*)alloc((size_t)64 * CD * 2);
    bf16* vW2T0 = (bf16*)alloc((size_t)64 * CD * 2);
    bf16* vW2T1 = (bf16*)alloc((size_t)64 * CD * 2);
    bf16* cm0 = (bf16*)alloc(E2M * 2);
    bf16* cm1 = (bf16*)alloc(E2M * 2);
    bf16* cmv0 = (bf16*)alloc(E2M * 2);
    bf16* y0  = (bf16*)alloc(E2M * 2);
    bf16* y1  = (bf16*)alloc(E2M * 2);
    int*  counts = (int*)alloc(512 * 4);
    int*  lists  = (int*)alloc((size_t)512 * 2048 * 4);
    bf16* qb     = (bf16*)alloc(E2M * 2);
    bf16* kb     = (bf16*)alloc(E2M * 2);
    bf16* vbT    = (bf16*)alloc(E2M * 2);
    bf16* ck0    = (bf16*)alloc(512 * 64 * 2);
    bf16* ck1    = (bf16*)alloc(512 * 64 * 2);
    bf16* Pbuf   = (bf16*)alloc((size_t)HEADS * N_TOK * 512 * 2);   // 33.6 MB
    // aliases
    bf16*  h0     = (bf16*)hreg;                   // 4 MB
    bf16*  h1     = h0 + (size_t)512 * CD;         // 4 MB
    float* part   = y;                             // sk_gemm partials (8 MB)
    float* Sc     = y;                             // cscore logits
    bf16*  qs0    = y0;                            // q split2 (y0/y1 free until Wo stage)
    bf16*  qs1    = y1;
    float* partL1 = (float*)Pbuf;                  // bigk partials 32 MB (= Pbuf size exactly)
    float* S      = (float*)kW1T0;                 // sel scores (67 MB over dead weight splits)
    bf16*  P      = Pbuf;
    bf16*  Opart  = kW1T0;                         // bf16 partials (33.5 MB, S dead after softmax)

    dim3 blk(256);
    if (off <= ws_size) {
        // ---------- fast path ----------
        split2_k<<<8192, 256, 0, stream>>>(x, xs0, xs1, (int)E2M);
        tsplit<2><<<dim3(32, 32), blk, 0, stream>>>(Wq, WqT0, WqT1, nullptr, DIM, DIM);
        tsplit<2><<<dim3(32, 32), blk, 0, stream>>>(Wk, WkT0, WkT1, nullptr, DIM, DIM);
        tsplit<1><<<dim3(32, 32), blk, 0, stream>>>(Wv, WvT, nullptr, nullptr, DIM, DIM);
        tsplit<2><<<dim3(32, 32), blk, 0, stream>>>(Wo, WoT0, WoT1, nullptr, DIM, DIM);
        tsplit<2><<<dim3(128, 128), blk, 0, stream>>>(kW1, kW1T0, kW1T1, nullptr, CD, CD);
        tsplit<1><<<dim3(128, 128), blk, 0, stream>>>(vW1, vW1T, nullptr, nullptr, CD, CD);
        tsplit<2><<<dim3(2, 128), blk, 0, stream>>>(kW2, kW2T0, kW2T1, nullptr, CD, 64);
        tsplit<2><<<dim3(2, 128), blk, 0, stream>>>(vW2, vW2T0, vW2T1, nullptr, CD, 64);

        // projections; q/k epilogues fuse RoPE -> qb/kb directly (no f32 q/k round-trip)
        gemm_mfma<4, 7><<<dim3(16, 32), blk, 0, stream>>>(xs0, xs1, nullptr, WqT0, WqT1, nullptr,
                                                          nullptr, (float*)qb, qs0, qs1, N_TOK, DIM, DIM, 0, nullptr, fc);
        gemm_mfma<4, 8><<<dim3(16, 32), blk, 0, stream>>>(xs0, xs1, nullptr, WkT0, WkT1, nullptr,
                                                          nullptr, (float*)kb, cm0, cm1, N_TOK, DIM, DIM, 0, pe, fc);
        gemm_mfma<1, 6><<<dim3(16, 32), blk, 0, stream>>>(xs0, nullptr, nullptr, WvT, nullptr, nullptr,
                                                          nullptr, v, cmv0, nullptr, N_TOK, DIM, DIM, 0, pe, nullptr);
        gate_gemm<<<2048, blk, 0, stream>>>(x, Wc, bc, gate);

        // k-compress: 128x128-tile split-K(4) L1 -> kredh -> split-K L2 (R17 config)
        gemm_bigk<3><<<dim3(32, 4, 4), blk, 0, stream>>>(cm0, cm1, kW1T0, kW1T1, partL1, 512, CD, CD);
        kredh<<<8192, 256, 0, stream>>>(partL1, kb1, h0, h1);
        sk_gemm<64><<<dim3(8, 64), blk, 0, stream>>>(h0, h1, kW2T0, kW2T1, part, 512, CD);
        skred<<<128, 256, 0, stream>>>(part, kb2, ck, ck0, ck1, 512, 64);

        // v-compress
        gemm_bigk<1><<<dim3(32, 4, 4), blk, 0, stream>>>(cmv0, nullptr, vW1T, nullptr, partL1, 512, CD, CD);
        kredh<<<8192, 256, 0, stream>>>(partL1, vb1, h0, h1);
        sk_gemm<64><<<dim3(8, 64), blk, 0, stream>>>(h0, h1, vW2T0, vW2T1, part, 512, CD);
        skred<<<128, 256, 0, stream>>>(part, vb2, cv, nullptr, nullptr, 512, 64);

        // cscore via MFMA (also zeroes counts), then softmax + rank-top8 + PV
        cscore_gemm<<<dim3(16, 16), blk, 0, stream>>>(qs0, qs1, ck0, ck1, Sc, counts);
        ctopk_pv<<<8192, 256, 0, stream>>>(Sc, cv, comp, idxb);

        // coalesced V transpose (RoPE for q/k already fused into projections)
        convert_vT<<<dim3(16, 32), blk, 0, stream>>>(v, vbT);

        build_lists<<<128, 256, 0, stream>>>(idxb, counts, lists);
        sel_scores<<<dim3(512, 64), 64, 0, stream>>>(qb, kb, counts, lists, S);
        sel_softmax<<<8192, 256, 0, stream>>>(S, P);
        sel_pv<<<dim3(512, 64), 64, 0, stream>>>(P, vbT, counts, lists, Opart);
        sel_combine<<<8192, 256, 0, stream>>>(Opart, comp, gate, y0, y1);

        gemm_mfma<3, 0><<<dim3(16, 32), blk, 0, stream>>>(y0, y1, nullptr, WoT0, WoT1, nullptr,
                                                          nullptr, out, nullptr, nullptr, N_TOK, DIM, DIM, 0, nullptr, nullptr);
    } else {
        // ---------- fallback: f32 path ----------
        char* p = (char*)d_ws;
        float* fq    = (float*)p;               p += E2M * 4;
        float* fk    = (float*)p;               p += E2M * 4;
        float* fv    = (float*)p;               p += E2M * 4;
        float* fgate = (float*)p;               p += N_TOK * 32 * 4;
        float* cmat  = (float*)p;               p += E2M * 4;
        float* hbuf  = (float*)p;               p += E2M * 4;
        float* fck   = (float*)p;               p += 512 * 64 * 4;
        float* fcv   = (float*)p;               p += 512 * 64 * 4;
        float* fcpr  = (float*)p;               p += (size_t)HEADS * N_TOK * WBLK * 4;
        int*   fidx  = (int*)p;
        float* fcomp = cmat;
        float* fy    = hbuf;

        gemm_f32<<<dim3(16, 32), blk, 0, stream>>>(x, Wq, nullptr, fq, N_TOK, DIM, DIM, 0);
        gemm_f32<<<dim3(16, 32), blk, 0, stream>>>(x, Wk, nullptr, fk, N_TOK, DIM, DIM, 0);
        gemm_f32<<<dim3(16, 32), blk, 0, stream>>>(x, Wv, nullptr, fv, N_TOK, DIM, DIM, 0);
        gemm_f32<<<dim3(1, 32),  blk, 0, stream>>>(x, Wc, bc, fgate, N_TOK, 2 * HEADS, DIM, 2);
        build_cmat<<<8192, 256, 0, stream>>>(fk, pe, cmat);
        gemm_f32<<<dim3(64, 8), blk, 0, stream>>>(cmat, kW1, kb1, hbuf, 512, CD, CD, 1);
        gemm_skinny64<<<512, blk, 0, stream>>>(hbuf, kW2, kb2, fck, CD);
        build_cmat<<<8192, 256, 0, stream>>>(fv, pe, cmat);
        gemm_f32<<<dim3(64, 8), blk, 0, stream>>>(cmat, vW1, vb1, hbuf, 512, CD, CD, 1);
        gemm_skinny64<<<512, blk, 0, stream>>>(hbuf, vW2, vb2, fcv, CD);
        cscore_topk<<<8192, 256, 0, stream>>>(fq, fck, fcpr, fidx);
        compressed_pv<<<8192, 256, 0, stream>>>(fcpr, fcv, fcomp);
        rope_ip<<<4096, 256, 0, stream>>>(fq, fk, fc);
        selected_attn<<<32768, 64, 0, stream>>>(fq, fk, fv, fidx, fcomp, fgate, fy);
        gemm_f32<<<dim3(16, 32), blk, 0, stream>>>(fy, Wo, nullptr, out, N_TOK, DIM, DIM, 0);
    }
}